// Round 1
// baseline (309.787 us; speedup 1.0000x reference)
//
#include <hip/hip_runtime.h>
#include <hip/hip_bf16.h>

// Round 9: double-buffered K-loop with counted vmcnt (T3-min + T4):
//   - LDS tiles x2 (48 KB): stage tile k+1 while MFMAing tile k
//   - raw s_barrier + asm "s_waitcnt vmcnt(6)" so the 6 in-flight
//     global_load_lds of the NEXT tile survive the barrier (the
//     __syncthreads path forces a vmcnt(0) drain = exposed latency
//     every K-step, which was the dominant stall)
//   - K-loop templated on KP (512/896) -> fully unrolled, static buf idx

#define B_SZ     4096
#define LSTM_N   400
#define NG       1600   // 4*LSTM
#define VOCAB    73
#define NATTN    10
#define CHARLEN  64
#define KP1      512    // padded 73+3+400  (mult of 64)
#define KP23     896    // padded 3+400+73+400 (mult of 64)

typedef _Float16 half8 __attribute__((ext_vector_type(8)));
typedef __attribute__((ext_vector_type(4))) float floatx4;

__device__ __forceinline__ void gload_lds16(const void* g, void* l) {
    __builtin_amdgcn_global_load_lds(
        (const __attribute__((address_space(1))) void*)g,
        (__attribute__((address_space(3))) void*)l, 16, 0, 0);
}

// [row][64-half] LDS tile, XOR-swizzled 16B granules within each 128B row:
// physical granule = logical granule ^ (row & 7)
__device__ __forceinline__ int lds_off(int r, int g) {
    return (r << 6) + ((((g ^ r) & 7)) << 3);
}

// ---------------------------------------------------------------- pack weights
// z=0: W1 gate-interleaved (Kp=512); z=1: W2; z=2: W3 (Kp=896); z=3: W_attn.
// Interleave: dest row n = 4u+g  <-  src row g*400+u.
__global__ __launch_bounds__(256) void pack_wall(const float* __restrict__ Wih1,
                                                 const float* __restrict__ Whh1,
                                                 const float* __restrict__ Wih2,
                                                 const float* __restrict__ Whh2,
                                                 const float* __restrict__ Wih3,
                                                 const float* __restrict__ Whh3,
                                                 const float* __restrict__ W_attn,
                                                 _Float16* __restrict__ W1,
                                                 _Float16* __restrict__ W2,
                                                 _Float16* __restrict__ W3,
                                                 _Float16* __restrict__ Wa)
{
    const int z = blockIdx.z;
    const int n = blockIdx.y;           // dest row
    const int k = blockIdx.x * 256 + threadIdx.x;
    if (z == 3) {
        if (n >= 64 || k >= KP1) return;
        float v = (n < 30 && k < 476) ? W_attn[(size_t)n * 476 + k] : 0.f;
        Wa[(size_t)n * KP1 + k] = (_Float16)v;
        return;
    }
    if (n >= NG) return;
    const int u = n >> 2, g = n & 3;
    const int src = g * 400 + u;        // original torch row
    if (z == 0) {
        if (k >= KP1) return;
        float v = 0.f;
        if (k < 76)           v = Wih1[(size_t)src * 76 + k];
        else if (k < 476)     v = Whh1[(size_t)src * 400 + (k - 76)];
        W1[(size_t)n * KP1 + k] = (_Float16)v;
    } else {
        if (k >= KP23) return;
        const float* Wih = (z == 1) ? Wih2 : Wih3;
        const float* Whh = (z == 1) ? Whh2 : Whh3;
        float v = 0.f;
        if (k < 476)          v = Wih[(size_t)src * 476 + k];
        else if (k < 876)     v = Whh[(size_t)src * 400 + (k - 476)];
        ((z == 1) ? W2 : W3)[(size_t)n * KP23 + k] = (_Float16)v;
    }
}

// ---------------------------------------------------------------- pack X/XA
__global__ __launch_bounds__(256) void pack_x(const float* __restrict__ w_prev,
                                              const float* __restrict__ inputs,
                                              const float* __restrict__ h1,
                                              const float* __restrict__ h2,
                                              const float* __restrict__ h3,
                                              _Float16* __restrict__ X1,
                                              _Float16* __restrict__ XA,
                                              _Float16* __restrict__ X2,
                                              _Float16* __restrict__ X3)
{
    const int b = blockIdx.y;
    const int k = blockIdx.x * 256 + threadIdx.x;
    if (k < KP1) {
        float v = 0.f;
        if (k < 73)        v = w_prev[(size_t)b * 73 + k];
        else if (k < 76)   v = inputs[(size_t)b * 3 + (k - 73)];
        else if (k < 476)  v = h1[(size_t)b * 400 + (k - 76)];
        X1[(size_t)b * KP1 + k] = (_Float16)v;
        if (k < 76 || k >= 476) XA[(size_t)b * KP1 + k] = (_Float16)v;
    }
    const int kk = k - KP1;
    if (kk >= 0 && kk < KP23) {
        if (kk >= 3 && kk < 476) return;   // h1n/h2n by epilogue, w by attn
        float v2 = 0.f, v3 = 0.f;
        if (kk < 3) { v2 = inputs[(size_t)b * 3 + kk]; v3 = v2; }
        else if (kk >= 476 && kk < 876) {
            v2 = h2[(size_t)b * 400 + (kk - 476)];
            v3 = h3[(size_t)b * 400 + (kk - 476)];
        }
        X2[(size_t)b * KP23 + kk] = (_Float16)v2;
        X3[(size_t)b * KP23 + kk] = (_Float16)v3;
    }
}

// ---------------------------------------------------------------- fused GEMM
// 64x128 tile: m = gate rows (4u+g interleaved), n = batch. BK=64, dbuf.
// Waves 2x2: each wave 32 rows x 64 batch = 2x4 frags.
// Epilogue: lane regs 0..3 = gates i,f,g,o of unit u -> LSTM pointwise.
template<int KP>
__global__ __launch_bounds__(256) void gemm_fused_t(const _Float16* __restrict__ Wm,
                                                    const _Float16* __restrict__ X,
                                                    const float* __restrict__ bias,
                                                    const float* __restrict__ c_in,
                                                    _Float16* __restrict__ d1, int ld1,
                                                    _Float16* __restrict__ d2, int ld2,
                                                    float* __restrict__ fout)
{
    __shared__ _Float16 As[2][64 * 64];    // W tile, 8 KB x2
    __shared__ _Float16 Bs[2][128 * 64];   // X tile, 16 KB x2

    const int t    = threadIdx.x;
    const int w    = t >> 6;
    const int lane = t & 63;
    const int quad = lane >> 4;
    const int l16  = lane & 15;
    const int m0   = blockIdx.y * 64;   // gate-row tile (0..1536)
    const int n0   = blockIdx.x * 128;  // batch tile
    const int wm   = (w >> 1) * 32;
    const int wn   = (w & 1) * 64;
    const int lr   = lane >> 3;             // 0..7 row-in-8
    const int gq   = (lane & 7) ^ lr;       // logical granule this lane fetches

    floatx4 acc[2][4] = {};

    // 6 global_load_lds per thread per tile (2 W + 4 X); LDS dest is
    // wave-uniform base, lane scatter via HW lane*16; source pre-swizzled.
    auto stage = [&](int sb, int k0) {
        const int cr = w * 16;
#pragma unroll
        for (int s = 0; s < 2; s++)
            gload_lds16(Wm + (size_t)(m0 + cr + s * 8 + lr) * KP + k0 + gq * 8,
                        &As[sb][(cr + s * 8) * 64]);
#pragma unroll
        for (int j = 0; j < 2; j++) {
            const int cr2 = (j * 4 + w) * 16;
#pragma unroll
            for (int s = 0; s < 2; s++)
                gload_lds16(X + (size_t)(n0 + cr2 + s * 8 + lr) * KP + k0 + gq * 8,
                            &Bs[sb][(cr2 + s * 8) * 64]);
        }
    };

    stage(0, 0);
    constexpr int NT = KP / 64;
#pragma unroll
    for (int kt = 0; kt < NT; kt++) {
        const int sb = kt & 1;
        if (kt + 1 < NT) {
            stage(sb ^ 1, (kt + 1) * 64);   // 6 more in flight
            asm volatile("s_waitcnt vmcnt(6)" ::: "memory");  // only THIS tile's done
        } else {
            asm volatile("s_waitcnt vmcnt(0)" ::: "memory");
        }
        __builtin_amdgcn_s_barrier();       // raw barrier: no implicit vmcnt(0)
        __builtin_amdgcn_sched_barrier(0);  // keep ds_reads below the barrier

#pragma unroll
        for (int h = 0; h < 2; h++) {
            half8 af[2], bf[4];
#pragma unroll
            for (int i = 0; i < 2; i++)
                af[i] = *(const half8*)(&As[sb][lds_off(wm + i * 16 + l16, h * 4 + quad)]);
#pragma unroll
            for (int i = 0; i < 4; i++)
                bf[i] = *(const half8*)(&Bs[sb][lds_off(wn + i * 16 + l16, h * 4 + quad)]);
#pragma unroll
            for (int mt = 0; mt < 2; mt++)
#pragma unroll
                for (int nt = 0; nt < 4; nt++)
                    acc[mt][nt] = __builtin_amdgcn_mfma_f32_16x16x32_f16(
                        af[mt], bf[nt], acc[mt][nt], 0, 0, 0);
        }
        __builtin_amdgcn_s_barrier();       // reads of buf done before overwrite
    }

#pragma unroll
    for (int mt = 0; mt < 2; mt++) {
        const int u = ((m0 + wm + mt * 16) >> 2) + quad;   // unit index, < 400
        const float bi  = bias[u];
        const float bff = bias[400 + u];
        const float bg  = bias[800 + u];
        const float bo  = bias[1200 + u];
#pragma unroll
        for (int nt = 0; nt < 4; nt++) {
            const int b = n0 + wn + nt * 16 + l16;         // batch index
            float gi = acc[mt][nt][0] + bi;
            float gf = acc[mt][nt][1] + bff;
            float gg = acc[mt][nt][2] + bg;
            float go = acc[mt][nt][3] + bo;
            float si = 1.f / (1.f + expf(-gi));
            float sf = 1.f / (1.f + expf(-gf));
            float so = 1.f / (1.f + expf(-go));
            float cn = sf * c_in[(size_t)b * LSTM_N + u] + si * tanhf(gg);
            float h  = so * tanhf(cn);
            if (fout) {
                fout[(size_t)b * LSTM_N + u] = h;
            } else {
                _Float16 hh = (_Float16)h;
                d1[(size_t)b * ld1 + u] = hh;
                if (d2) d2[(size_t)b * ld2 + u] = hh;
            }
        }
    }
}

// ---------------------------------------------------------------- plain GEMM
// Attention params: C[n_batch*32 + m] = sum_k Wa[m,k]*XA[n,k] + bias[m], m<30.
// Same 64x128 dbuf structure; grid (32 batch-tiles, 1 row-tile). K=512.
__global__ __launch_bounds__(256) void gemm_plain(const _Float16* __restrict__ Wa,
                                                  const _Float16* __restrict__ XA,
                                                  const float* __restrict__ bias,
                                                  float* __restrict__ C)
{
    __shared__ _Float16 As[2][64 * 64];
    __shared__ _Float16 Bs[2][128 * 64];

    const int t    = threadIdx.x;
    const int w    = t >> 6;
    const int lane = t & 63;
    const int quad = lane >> 4;
    const int l16  = lane & 15;
    const int n0   = blockIdx.x * 128;
    const int wm   = (w >> 1) * 32;
    const int wn   = (w & 1) * 64;
    const int lr   = lane >> 3;
    const int gq   = (lane & 7) ^ lr;

    floatx4 acc[2][4] = {};

    auto stage = [&](int sb, int k0) {
        const int cr = w * 16;
#pragma unroll
        for (int s = 0; s < 2; s++)
            gload_lds16(Wa + (size_t)(cr + s * 8 + lr) * KP1 + k0 + gq * 8,
                        &As[sb][(cr + s * 8) * 64]);
#pragma unroll
        for (int j = 0; j < 2; j++) {
            const int cr2 = (j * 4 + w) * 16;
#pragma unroll
            for (int s = 0; s < 2; s++)
                gload_lds16(XA + (size_t)(n0 + cr2 + s * 8 + lr) * KP1 + k0 + gq * 8,
                            &Bs[sb][(cr2 + s * 8) * 64]);
        }
    };

    stage(0, 0);
    constexpr int NT = KP1 / 64;
#pragma unroll
    for (int kt = 0; kt < NT; kt++) {
        const int sb = kt & 1;
        if (kt + 1 < NT) {
            stage(sb ^ 1, (kt + 1) * 64);
            asm volatile("s_waitcnt vmcnt(6)" ::: "memory");
        } else {
            asm volatile("s_waitcnt vmcnt(0)" ::: "memory");
        }
        __builtin_amdgcn_s_barrier();
        __builtin_amdgcn_sched_barrier(0);

#pragma unroll
        for (int h = 0; h < 2; h++) {
            half8 af[2], bf[4];
#pragma unroll
            for (int i = 0; i < 2; i++)
                af[i] = *(const half8*)(&As[sb][lds_off(wm + i * 16 + l16, h * 4 + quad)]);
#pragma unroll
            for (int i = 0; i < 4; i++)
                bf[i] = *(const half8*)(&Bs[sb][lds_off(wn + i * 16 + l16, h * 4 + quad)]);
#pragma unroll
            for (int mt = 0; mt < 2; mt++)
#pragma unroll
                for (int nt = 0; nt < 4; nt++)
                    acc[mt][nt] = __builtin_amdgcn_mfma_f32_16x16x32_f16(
                        af[mt], bf[nt], acc[mt][nt], 0, 0, 0);
        }
        __builtin_amdgcn_s_barrier();
    }

#pragma unroll
    for (int mt = 0; mt < 2; mt++) {
#pragma unroll
        for (int r = 0; r < 4; r++) {
            const int m = wm + mt * 16 + quad * 4 + r;
            if (m >= 30) continue;
            const float bv = bias[m];
#pragma unroll
            for (int nt = 0; nt < 4; nt++) {
                const int b = n0 + wn + nt * 16 + l16;
                C[(size_t)b * 32 + m] = acc[mt][nt][r] + bv;
            }
        }
    }
}

// ---------------------------------------------------------------- attn phi+w
// wave = one batch row; 4 waves/block; grid B/4.
__global__ __launch_bounds__(256) void attn_phi(const float* __restrict__ AP,
                                                const float* __restrict__ kappa,
                                                const float* __restrict__ AV,
                                                const int* __restrict__ alen,
                                                _Float16* __restrict__ X2,
                                                _Float16* __restrict__ X3)
{
    __shared__ float prm[4][32];
    __shared__ float phi_s[4][CHARLEN];

    const int t = threadIdx.x;
    const int wave = t >> 6;
    const int lane = t & 63;
    const int b = blockIdx.x * 4 + wave;

    if (lane < 30) {
        float p  = AP[(size_t)b * 32 + lane];
        float sp = (p > 20.f) ? p : log1pf(expf(p));
        float v;
        if (lane < 10)      v = sp;                          // alpha
        else if (lane < 20) v = fmaxf(sp, 0.01f);            // beta
        else                v = kappa[(size_t)b * NATTN + (lane - 20)] + sp * (1.f / 25.f);
        prm[wave][lane] = v;
    }
    __syncthreads();

    const int len = alen[b];
    {
        int c = lane;
        float phi = 0.f;
#pragma unroll
        for (int j = 0; j < NATTN; j++) {
            float d = prm[wave][20 + j] - (float)c;
            phi += prm[wave][j] * expf(-d * d / prm[wave][10 + j]);
        }
        phi_s[wave][c] = (c < len) ? phi : 0.f;
    }
    __syncthreads();

    for (int v0 = 0; v0 < VOCAB; v0 += 64) {   // VOCAB=73 > 64 lanes
        const int v = v0 + lane;
        if (v < VOCAB) {
            const float* avb = AV + (size_t)b * CHARLEN * VOCAB + v;
            float s = 0.f;
            for (int c = 0; c < len; c++)      // len is wave-uniform
                s += phi_s[wave][c] * avb[(size_t)c * VOCAB];
            _Float16 wv = (_Float16)s;
            X2[(size_t)b * KP23 + 403 + v] = wv;
            X3[(size_t)b * KP23 + 403 + v] = wv;
        }
    }
}

// ---------------------------------------------------------------- launch
extern "C" void kernel_launch(void* const* d_in, const int* in_sizes, int n_in,
                              void* d_out, int out_size, void* d_ws, size_t ws_size,
                              hipStream_t stream)
{
    const float* inputs = (const float*)d_in[0];
    const float* h1     = (const float*)d_in[1];
    const float* c1     = (const float*)d_in[2];
    const float* h2     = (const float*)d_in[3];
    const float* c2     = (const float*)d_in[4];
    const float* h3     = (const float*)d_in[5];
    const float* c3     = (const float*)d_in[6];
    const float* kappa  = (const float*)d_in[7];
    const float* w_prev = (const float*)d_in[8];
    const float* AV     = (const float*)d_in[9];
    const int*   alen   = (const int*)d_in[10];
    const float* W_ih1  = (const float*)d_in[11];
    const float* W_hh1  = (const float*)d_in[12];
    const float* b1     = (const float*)d_in[13];
    const float* W_attn = (const float*)d_in[14];
    const float* b_attn = (const float*)d_in[15];
    const float* W_ih2  = (const float*)d_in[16];
    const float* W_hh2  = (const float*)d_in[17];
    const float* b2     = (const float*)d_in[18];
    const float* W_ih3  = (const float*)d_in[19];
    const float* W_hh3  = (const float*)d_in[20];
    const float* b3     = (const float*)d_in[21];
    float* out = (float*)d_out;

    char* p = (char*)d_ws;
    _Float16* X1 = (_Float16*)p; p += (size_t)B_SZ * KP1 * 2;
    _Float16* XA = (_Float16*)p; p += (size_t)B_SZ * KP1 * 2;   // attn input
    _Float16* X2 = (_Float16*)p; p += (size_t)B_SZ * KP23 * 2;
    _Float16* X3 = (_Float16*)p; p += (size_t)B_SZ * KP23 * 2;
    _Float16* W1 = (_Float16*)p; p += (size_t)NG * KP1 * 2;
    _Float16* W2 = (_Float16*)p; p += (size_t)NG * KP23 * 2;
    _Float16* W3 = (_Float16*)p; p += (size_t)NG * KP23 * 2;
    _Float16* Wa = (_Float16*)p; p += (size_t)64 * KP1 * 2;
    float* AP = (float*)p;                                       // B*32 fp32

    pack_wall<<<dim3(4, NG, 4), 256, 0, stream>>>(W_ih1, W_hh1, W_ih2, W_hh2,
                                                  W_ih3, W_hh3, W_attn,
                                                  W1, W2, W3, Wa);
    pack_x<<<dim3((KP1 + KP23 + 255) / 256, B_SZ), 256, 0, stream>>>(
        w_prev, inputs, h1, h2, h3, X1, XA, X2, X3);

    const dim3 fgrid(B_SZ / 128, NG / 64);   // 32 batch-tiles x 25 row-tiles

    // LSTM1: h1n -> XA h-region (attn input) + X2 cols 3..
    gemm_fused_t<KP1><<<fgrid, 256, 0, stream>>>(W1, X1, b1, c1,
                                                 XA + 76, KP1, X2 + 3, KP23, nullptr);
    // attention params: AP[b,0:30] = Wa * XA[b] + b_attn
    gemm_plain<<<dim3(B_SZ / 128, 1), 256, 0, stream>>>(Wa, XA, b_attn, AP);
    // phi + einsum -> w into X2, X3
    attn_phi<<<B_SZ / 4, 256, 0, stream>>>(AP, kappa, AV, alen, X2, X3);
    // LSTM2: h2n -> X3 cols 3..
    gemm_fused_t<KP23><<<fgrid, 256, 0, stream>>>(W2, X2, b2, c2,
                                                  X3 + 3, KP23, nullptr, 0, nullptr);
    // LSTM3: h3n -> out (fp32)
    gemm_fused_t<KP23><<<fgrid, 256, 0, stream>>>(W3, X3, b3, c3,
                                                  nullptr, 0, nullptr, 0, out);
}

// Round 2
// 305.928 us; speedup vs baseline: 1.0126x; 1.0126x over previous
//
#include <hip/hip_runtime.h>
#include <hip/hip_bf16.h>

// Round 10: descattered epilogue I/O (LDS transpose):
//   - K-layouts of XA/X2/X3 permuted so the h-region starts at col 0
//     (weight packs permuted to match -> GEMM math unchanged)
//   - gemm_fused epilogue: c_in staged via float4->LDS; h written to an
//     LDS [b][u] tile then stored as contiguous 16B runs per batch row
//     (replaces millions of strided 2B/4B global accesses)
//   - gemm_plain epilogue: same LDS transpose, 16B-run C stores
//   - K-loop keeps the round-9 dbuf + counted vmcnt structure

#define B_SZ     4096
#define LSTM_N   400
#define NG       1600   // 4*LSTM
#define VOCAB    73
#define NATTN    10
#define CHARLEN  64
#define KP1      512    // padded  (mult of 64)
#define KP23     896    // padded  (mult of 64)

typedef _Float16 half8 __attribute__((ext_vector_type(8)));
typedef _Float16 half4 __attribute__((ext_vector_type(4)));
typedef __attribute__((ext_vector_type(4))) float floatx4;

__device__ __forceinline__ void gload_lds16(const void* g, void* l) {
    __builtin_amdgcn_global_load_lds(
        (const __attribute__((address_space(1))) void*)g,
        (__attribute__((address_space(3))) void*)l, 16, 0, 0);
}

// [row][64-half] LDS tile, XOR-swizzled 16B granules within each 128B row:
// physical granule = logical granule ^ (row & 7)
__device__ __forceinline__ int lds_off(int r, int g) {
    return (r << 6) + ((((g ^ r) & 7)) << 3);
}

// ---------------------------------------------------------------- pack weights
// Layouts (columns of X buffers / rows of W packs use the SAME permutation):
//   X1 (KP1):  [w_prev 0..73 | inputs 73..76 | h1 76..476 | 0pad]
//   XA (KP1):  [h1n 0..400 | w_prev 400..473 | inputs 473..476 | 0pad]
//   X2 (KP23): [h1n 0..400 | inputs 400..403 | w 403..476 | h2 476..876 | 0pad]
//   X3 (KP23): [h2n 0..400 | inputs 400..403 | w 403..476 | h3 476..876 | 0pad]
// Gate interleave: dest row n = 4u+g  <-  src row g*400+u.
__global__ __launch_bounds__(256) void pack_wall(const float* __restrict__ Wih1,
                                                 const float* __restrict__ Whh1,
                                                 const float* __restrict__ Wih2,
                                                 const float* __restrict__ Whh2,
                                                 const float* __restrict__ Wih3,
                                                 const float* __restrict__ Whh3,
                                                 const float* __restrict__ W_attn,
                                                 _Float16* __restrict__ W1,
                                                 _Float16* __restrict__ W2,
                                                 _Float16* __restrict__ W3,
                                                 _Float16* __restrict__ Wa)
{
    const int z = blockIdx.z;
    const int n = blockIdx.y;           // dest row
    const int k = blockIdx.x * 256 + threadIdx.x;
    if (z == 3) {
        if (n >= 64 || k >= KP1) return;
        float v = 0.f;
        if (n < 30) {   // src cols: [w_prev 0..73 | inputs 73..76 | h1n 76..476]
            if (k < 400)      v = W_attn[(size_t)n * 476 + 76 + k];
            else if (k < 473) v = W_attn[(size_t)n * 476 + (k - 400)];
            else if (k < 476) v = W_attn[(size_t)n * 476 + 73 + (k - 473)];
        }
        Wa[(size_t)n * KP1 + k] = (_Float16)v;
        return;
    }
    if (n >= NG) return;
    const int u = n >> 2, g = n & 3;
    const int src = g * 400 + u;        // original torch row
    if (z == 0) {
        if (k >= KP1) return;
        float v = 0.f;
        if (k < 76)           v = Wih1[(size_t)src * 76 + k];
        else if (k < 476)     v = Whh1[(size_t)src * 400 + (k - 76)];
        W1[(size_t)n * KP1 + k] = (_Float16)v;
    } else {
        if (k >= KP23) return;
        const float* Wih = (z == 1) ? Wih2 : Wih3;
        const float* Whh = (z == 1) ? Whh2 : Whh3;
        // src Wih cols: [inputs 0..3 | h 3..403 | w 403..476]
        float v = 0.f;
        if (k < 400)          v = Wih[(size_t)src * 476 + 3 + k];
        else if (k < 403)     v = Wih[(size_t)src * 476 + (k - 400)];
        else if (k < 476)     v = Wih[(size_t)src * 476 + k];
        else if (k < 876)     v = Whh[(size_t)src * 400 + (k - 476)];
        ((z == 1) ? W2 : W3)[(size_t)n * KP23 + k] = (_Float16)v;
    }
}

// ---------------------------------------------------------------- pack X/XA
__global__ __launch_bounds__(256) void pack_x(const float* __restrict__ w_prev,
                                              const float* __restrict__ inputs,
                                              const float* __restrict__ h1,
                                              const float* __restrict__ h2,
                                              const float* __restrict__ h3,
                                              _Float16* __restrict__ X1,
                                              _Float16* __restrict__ XA,
                                              _Float16* __restrict__ X2,
                                              _Float16* __restrict__ X3)
{
    const int b = blockIdx.y;
    const int k = blockIdx.x * 256 + threadIdx.x;
    if (k < KP1) {
        float v = 0.f;
        if (k < 73)        v = w_prev[(size_t)b * 73 + k];
        else if (k < 76)   v = inputs[(size_t)b * 3 + (k - 73)];
        else if (k < 476)  v = h1[(size_t)b * 400 + (k - 76)];
        X1[(size_t)b * KP1 + k] = (_Float16)v;
        if (k >= 400) {    // XA cols 400.. ; h1n region [0,400) by LSTM1
            float va = 0.f;
            if (k < 473)      va = w_prev[(size_t)b * 73 + (k - 400)];
            else if (k < 476) va = inputs[(size_t)b * 3 + (k - 473)];
            XA[(size_t)b * KP1 + k] = (_Float16)va;
        }
    }
    const int kk = k - KP1;
    if (kk >= 400 && kk < KP23) {
        if (kk >= 403 && kk < 476) return;   // w region by attn
        float v2 = 0.f, v3 = 0.f;
        if (kk < 403) { v2 = inputs[(size_t)b * 3 + (kk - 400)]; v3 = v2; }
        else if (kk < 876) {
            v2 = h2[(size_t)b * 400 + (kk - 476)];
            v3 = h3[(size_t)b * 400 + (kk - 476)];
        }
        X2[(size_t)b * KP23 + kk] = (_Float16)v2;
        X3[(size_t)b * KP23 + kk] = (_Float16)v3;
    }
}

// ---------------------------------------------------------------- fused GEMM
// 64x128 tile: m = gate rows (4u+g interleaved), n = batch. BK=64, dbuf.
// Waves 2x2: each wave 32 rows x 64 batch = 2x4 frags.
// Epilogue: lane regs 0..3 = gates i,f,g,o of unit u -> LSTM pointwise,
// then LDS-transpose so global I/O is contiguous 16B runs per batch row.
template<int KP>
__global__ __launch_bounds__(256) void gemm_fused_t(const _Float16* __restrict__ Wm,
                                                    const _Float16* __restrict__ X,
                                                    const float* __restrict__ bias,
                                                    const float* __restrict__ c_in,
                                                    _Float16* __restrict__ d1, int ld1,
                                                    _Float16* __restrict__ d2, int ld2,
                                                    float* __restrict__ fout)
{
    __shared__ _Float16 As[2][64 * 64];    // W tile, 8 KB x2   (epilogue: Hs)
    __shared__ _Float16 Bs[2][128 * 64];   // X tile, 16 KB x2  (epilogue: Cs)

    const int t    = threadIdx.x;
    const int w    = t >> 6;
    const int lane = t & 63;
    const int quad = lane >> 4;
    const int l16  = lane & 15;
    const int m0   = blockIdx.y * 64;   // gate-row tile
    const int n0   = blockIdx.x * 128;  // batch tile
    const int wm   = (w >> 1) * 32;
    const int wn   = (w & 1) * 64;
    const int lr   = lane >> 3;             // 0..7 row-in-8
    const int gq   = (lane & 7) ^ lr;       // logical granule this lane fetches

    floatx4 acc[2][4] = {};

    auto stage = [&](int sb, int k0) {
        const int cr = w * 16;
#pragma unroll
        for (int s = 0; s < 2; s++)
            gload_lds16(Wm + (size_t)(m0 + cr + s * 8 + lr) * KP + k0 + gq * 8,
                        &As[sb][(cr + s * 8) * 64]);
#pragma unroll
        for (int j = 0; j < 2; j++) {
            const int cr2 = (j * 4 + w) * 16;
#pragma unroll
            for (int s = 0; s < 2; s++)
                gload_lds16(X + (size_t)(n0 + cr2 + s * 8 + lr) * KP + k0 + gq * 8,
                            &Bs[sb][(cr2 + s * 8) * 64]);
        }
    };

    stage(0, 0);
    constexpr int NT = KP / 64;
#pragma unroll
    for (int kt = 0; kt < NT; kt++) {
        const int sb = kt & 1;
        if (kt + 1 < NT) {
            stage(sb ^ 1, (kt + 1) * 64);   // 6 more in flight
            asm volatile("s_waitcnt vmcnt(6)" ::: "memory");
        } else {
            asm volatile("s_waitcnt vmcnt(0)" ::: "memory");
        }
        __builtin_amdgcn_s_barrier();
        __builtin_amdgcn_sched_barrier(0);

#pragma unroll
        for (int h = 0; h < 2; h++) {
            half8 af[2], bf[4];
#pragma unroll
            for (int i = 0; i < 2; i++)
                af[i] = *(const half8*)(&As[sb][lds_off(wm + i * 16 + l16, h * 4 + quad)]);
#pragma unroll
            for (int i = 0; i < 4; i++)
                bf[i] = *(const half8*)(&Bs[sb][lds_off(wn + i * 16 + l16, h * 4 + quad)]);
#pragma unroll
            for (int mt = 0; mt < 2; mt++)
#pragma unroll
                for (int nt = 0; nt < 4; nt++)
                    acc[mt][nt] = __builtin_amdgcn_mfma_f32_16x16x32_f16(
                        af[mt], bf[nt], acc[mt][nt], 0, 0, 0);
        }
        __builtin_amdgcn_s_barrier();
    }
    __builtin_amdgcn_sched_barrier(0);

    // ---------------- epilogue: descattered I/O via LDS transpose ----------
    const int u0 = m0 >> 2;                   // first unit of this block
    float*    Cs   = (float*)(&Bs[0][0]);     // [128][20] f32 (10.2 KB)
    _Float16* Hs16 = (_Float16*)(&As[0][0]);  // [128][24] f16 (6 KB)
    float*    Hs32 = (float*)(&As[0][0]);     // [128][20] f32 (10.2 KB)
    {   // stage c tile, 2 x float4 per thread, 32B runs per batch row
        const int bl = t >> 1;
        const int j0 = (t & 1) * 2;
#pragma unroll
        for (int j = 0; j < 2; j++) {
            floatx4 cv = *(const floatx4*)(c_in + (size_t)(n0 + bl) * LSTM_N
                                           + u0 + (j0 + j) * 4);
            *(floatx4*)(Cs + bl * 20 + (j0 + j) * 4) = cv;
        }
    }
    __syncthreads();

#pragma unroll
    for (int mt = 0; mt < 2; mt++) {
        const int ul = (wm >> 2) + mt * 4 + quad;   // 0..15 local unit
        const int u  = u0 + ul;
        const float bi  = bias[u];
        const float bff = bias[400 + u];
        const float bg  = bias[800 + u];
        const float bo  = bias[1200 + u];
#pragma unroll
        for (int nt = 0; nt < 4; nt++) {
            const int bl = wn + nt * 16 + l16;      // local batch index
            float gi = acc[mt][nt][0] + bi;
            float gf = acc[mt][nt][1] + bff;
            float gg = acc[mt][nt][2] + bg;
            float go = acc[mt][nt][3] + bo;
            float si = 1.f / (1.f + expf(-gi));
            float sf = 1.f / (1.f + expf(-gf));
            float so = 1.f / (1.f + expf(-go));
            float cn = sf * Cs[bl * 20 + ul] + si * tanhf(gg);
            float h  = so * tanhf(cn);
            if (fout) Hs32[bl * 20 + ul] = h;
            else      Hs16[bl * 24 + ul] = (_Float16)h;
        }
    }
    __syncthreads();

    if (fout) {   // fp32 out: 64B per batch row, 2 x float4 per thread
        const int bl = t >> 1;
        const int p0 = (t & 1) * 2;
#pragma unroll
        for (int j = 0; j < 2; j++) {
            floatx4 hv = *(const floatx4*)(Hs32 + bl * 20 + (p0 + j) * 4);
            *(floatx4*)(fout + (size_t)(n0 + bl) * LSTM_N + u0 + (p0 + j) * 4) = hv;
        }
    } else {      // fp16: 32B per batch row, 1 x half8 per thread per dest
        const int bl = t >> 1;
        const int p  = t & 1;
        half8 hv = *(const half8*)(Hs16 + bl * 24 + p * 8);
        *(half8*)(d1 + (size_t)(n0 + bl) * ld1 + u0 + p * 8) = hv;
        if (d2) *(half8*)(d2 + (size_t)(n0 + bl) * ld2 + u0 + p * 8) = hv;
    }
}

// ---------------------------------------------------------------- plain GEMM
// Attention params: C[b*32 + m] = sum_k Wa[m,k]*XA[b,k] + bias[m], m<30.
// Same dbuf structure; epilogue LDS-transposed to 16B-run stores.
__global__ __launch_bounds__(256) void gemm_plain(const _Float16* __restrict__ Wa,
                                                  const _Float16* __restrict__ XA,
                                                  const float* __restrict__ bias,
                                                  float* __restrict__ C)
{
    __shared__ _Float16 As[2][64 * 64];
    __shared__ _Float16 Bs[2][128 * 64];

    const int t    = threadIdx.x;
    const int w    = t >> 6;
    const int lane = t & 63;
    const int quad = lane >> 4;
    const int l16  = lane & 15;
    const int n0   = blockIdx.x * 128;
    const int wm   = (w >> 1) * 32;
    const int wn   = (w & 1) * 64;
    const int lr   = lane >> 3;
    const int gq   = (lane & 7) ^ lr;

    floatx4 acc[2][4] = {};

    auto stage = [&](int sb, int k0) {
        const int cr = w * 16;
#pragma unroll
        for (int s = 0; s < 2; s++)
            gload_lds16(Wa + (size_t)(cr + s * 8 + lr) * KP1 + k0 + gq * 8,
                        &As[sb][(cr + s * 8) * 64]);
#pragma unroll
        for (int j = 0; j < 2; j++) {
            const int cr2 = (j * 4 + w) * 16;
#pragma unroll
            for (int s = 0; s < 2; s++)
                gload_lds16(XA + (size_t)(n0 + cr2 + s * 8 + lr) * KP1 + k0 + gq * 8,
                            &Bs[sb][(cr2 + s * 8) * 64]);
        }
    };

    stage(0, 0);
    constexpr int NT = KP1 / 64;
#pragma unroll
    for (int kt = 0; kt < NT; kt++) {
        const int sb = kt & 1;
        if (kt + 1 < NT) {
            stage(sb ^ 1, (kt + 1) * 64);
            asm volatile("s_waitcnt vmcnt(6)" ::: "memory");
        } else {
            asm volatile("s_waitcnt vmcnt(0)" ::: "memory");
        }
        __builtin_amdgcn_s_barrier();
        __builtin_amdgcn_sched_barrier(0);

#pragma unroll
        for (int h = 0; h < 2; h++) {
            half8 af[2], bf[4];
#pragma unroll
            for (int i = 0; i < 2; i++)
                af[i] = *(const half8*)(&As[sb][lds_off(wm + i * 16 + l16, h * 4 + quad)]);
#pragma unroll
            for (int i = 0; i < 4; i++)
                bf[i] = *(const half8*)(&Bs[sb][lds_off(wn + i * 16 + l16, h * 4 + quad)]);
#pragma unroll
            for (int mt = 0; mt < 2; mt++)
#pragma unroll
                for (int nt = 0; nt < 4; nt++)
                    acc[mt][nt] = __builtin_amdgcn_mfma_f32_16x16x32_f16(
                        af[mt], bf[nt], acc[mt][nt], 0, 0, 0);
        }
        __builtin_amdgcn_s_barrier();
    }
    __builtin_amdgcn_sched_barrier(0);

    // epilogue: transpose through LDS, store 128B runs per batch row
    float* Ps = (float*)(&Bs[0][0]);   // [128][36] f32 (18.4 KB)
    if (wm == 0) {                     // waves 0,1 hold m < 32
#pragma unroll
        for (int mt = 0; mt < 2; mt++)
#pragma unroll
            for (int r = 0; r < 4; r++) {
                const int m = mt * 16 + quad * 4 + r;
                const float bv = (m < 30) ? bias[m] : 0.f;
#pragma unroll
                for (int nt = 0; nt < 4; nt++) {
                    const int bl = wn + nt * 16 + l16;
                    Ps[bl * 36 + m] = acc[mt][nt][r] + bv;
                }
            }
    }
    __syncthreads();
    {
        const int bl = t >> 1;
        const int p0 = (t & 1) * 4;
#pragma unroll
        for (int j = 0; j < 4; j++) {
            floatx4 v = *(const floatx4*)(Ps + bl * 36 + (p0 + j) * 4);
            *(floatx4*)(C + (size_t)(n0 + bl) * 32 + (p0 + j) * 4) = v;
        }
    }
}

// ---------------------------------------------------------------- attn phi+w
// wave = one batch row; 4 waves/block; grid B/4.
__global__ __launch_bounds__(256) void attn_phi(const float* __restrict__ AP,
                                                const float* __restrict__ kappa,
                                                const float* __restrict__ AV,
                                                const int* __restrict__ alen,
                                                _Float16* __restrict__ X2,
                                                _Float16* __restrict__ X3)
{
    __shared__ float prm[4][32];
    __shared__ float phi_s[4][CHARLEN];

    const int t = threadIdx.x;
    const int wave = t >> 6;
    const int lane = t & 63;
    const int b = blockIdx.x * 4 + wave;

    if (lane < 30) {
        float p  = AP[(size_t)b * 32 + lane];
        float sp = (p > 20.f) ? p : log1pf(expf(p));
        float v;
        if (lane < 10)      v = sp;                          // alpha
        else if (lane < 20) v = fmaxf(sp, 0.01f);            // beta
        else                v = kappa[(size_t)b * NATTN + (lane - 20)] + sp * (1.f / 25.f);
        prm[wave][lane] = v;
    }
    __syncthreads();

    const int len = alen[b];
    {
        int c = lane;
        float phi = 0.f;
#pragma unroll
        for (int j = 0; j < NATTN; j++) {
            float d = prm[wave][20 + j] - (float)c;
            phi += prm[wave][j] * expf(-d * d / prm[wave][10 + j]);
        }
        phi_s[wave][c] = (c < len) ? phi : 0.f;
    }
    __syncthreads();

    for (int v0 = 0; v0 < VOCAB; v0 += 64) {   // VOCAB=73 > 64 lanes
        const int v = v0 + lane;
        if (v < VOCAB) {
            const float* avb = AV + (size_t)b * CHARLEN * VOCAB + v;
            float s = 0.f;
            for (int c = 0; c < len; c++)      // len is wave-uniform
                s += phi_s[wave][c] * avb[(size_t)c * VOCAB];
            _Float16 wv = (_Float16)s;
            X2[(size_t)b * KP23 + 403 + v] = wv;
            X3[(size_t)b * KP23 + 403 + v] = wv;
        }
    }
}

// ---------------------------------------------------------------- launch
extern "C" void kernel_launch(void* const* d_in, const int* in_sizes, int n_in,
                              void* d_out, int out_size, void* d_ws, size_t ws_size,
                              hipStream_t stream)
{
    const float* inputs = (const float*)d_in[0];
    const float* h1     = (const float*)d_in[1];
    const float* c1     = (const float*)d_in[2];
    const float* h2     = (const float*)d_in[3];
    const float* c2     = (const float*)d_in[4];
    const float* h3     = (const float*)d_in[5];
    const float* c3     = (const float*)d_in[6];
    const float* kappa  = (const float*)d_in[7];
    const float* w_prev = (const float*)d_in[8];
    const float* AV     = (const float*)d_in[9];
    const int*   alen   = (const int*)d_in[10];
    const float* W_ih1  = (const float*)d_in[11];
    const float* W_hh1  = (const float*)d_in[12];
    const float* b1     = (const float*)d_in[13];
    const float* W_attn = (const float*)d_in[14];
    const float* b_attn = (const float*)d_in[15];
    const float* W_ih2  = (const float*)d_in[16];
    const float* W_hh2  = (const float*)d_in[17];
    const float* b2     = (const float*)d_in[18];
    const float* W_ih3  = (const float*)d_in[19];
    const float* W_hh3  = (const float*)d_in[20];
    const float* b3     = (const float*)d_in[21];
    float* out = (float*)d_out;

    char* p = (char*)d_ws;
    _Float16* X1 = (_Float16*)p; p += (size_t)B_SZ * KP1 * 2;
    _Float16* XA = (_Float16*)p; p += (size_t)B_SZ * KP1 * 2;   // attn input
    _Float16* X2 = (_Float16*)p; p += (size_t)B_SZ * KP23 * 2;
    _Float16* X3 = (_Float16*)p; p += (size_t)B_SZ * KP23 * 2;
    _Float16* W1 = (_Float16*)p; p += (size_t)NG * KP1 * 2;
    _Float16* W2 = (_Float16*)p; p += (size_t)NG * KP23 * 2;
    _Float16* W3 = (_Float16*)p; p += (size_t)NG * KP23 * 2;
    _Float16* Wa = (_Float16*)p; p += (size_t)64 * KP1 * 2;
    float* AP = (float*)p;                                       // B*32 fp32

    pack_wall<<<dim3(4, NG, 4), 256, 0, stream>>>(W_ih1, W_hh1, W_ih2, W_hh2,
                                                  W_ih3, W_hh3, W_attn,
                                                  W1, W2, W3, Wa);
    pack_x<<<dim3((KP1 + KP23 + 255) / 256, B_SZ), 256, 0, stream>>>(
        w_prev, inputs, h1, h2, h3, X1, XA, X2, X3);

    const dim3 fgrid(B_SZ / 128, NG / 64);   // 32 batch-tiles x 25 row-tiles

    // LSTM1: h1n -> XA col 0 (attn input) + X2 col 0
    gemm_fused_t<KP1><<<fgrid, 256, 0, stream>>>(W1, X1, b1, c1,
                                                 XA, KP1, X2, KP23, nullptr);
    // attention params: AP[b,0:30] = Wa * XA[b] + b_attn
    gemm_plain<<<dim3(B_SZ / 128, 1), 256, 0, stream>>>(Wa, XA, b_attn, AP);
    // phi + einsum -> w into X2, X3
    attn_phi<<<B_SZ / 4, 256, 0, stream>>>(AP, kappa, AV, alen, X2, X3);
    // LSTM2: h2n -> X3 col 0
    gemm_fused_t<KP23><<<fgrid, 256, 0, stream>>>(W2, X2, b2, c2,
                                                  X3, KP23, nullptr, 0, nullptr);
    // LSTM3: h3n -> out (fp32)
    gemm_fused_t<KP23><<<fgrid, 256, 0, stream>>>(W3, X3, b3, c3,
                                                  nullptr, 0, nullptr, 0, out);
}

// Round 3
// 298.872 us; speedup vs baseline: 1.0365x; 1.0236x over previous
//
#include <hip/hip_runtime.h>
#include <hip/hip_bf16.h>

// Round 11: chain-level restructure:
//   - pack_wall+pack_x -> ONE flat pack kernel, 8 elem/thread (half8 stores),
//     4056 blocks vs 50176 across two kernels
//   - gemm_plain (4096x30, K=512) folded into attn_phi as LDS-staged wave
//     dot-products + butterfly reduce (one dispatch + AP round-trip removed)
//   - s_setprio(1) around MFMA cluster in fused GEMMs (T5; dbuf role-split)
//   - GEMM structure otherwise unchanged from round 10 (dbuf + counted vmcnt,
//     descattered epilogue)

#define B_SZ     4096
#define LSTM_N   400
#define NG       1600   // 4*LSTM
#define VOCAB    73
#define NATTN    10
#define CHARLEN  64
#define KP1      512    // padded  (mult of 64)
#define KP23     896    // padded  (mult of 64)

typedef _Float16 half8 __attribute__((ext_vector_type(8)));
typedef __attribute__((ext_vector_type(4))) float floatx4;

__device__ __forceinline__ void gload_lds16(const void* g, void* l) {
    __builtin_amdgcn_global_load_lds(
        (const __attribute__((address_space(1))) void*)g,
        (__attribute__((address_space(3))) void*)l, 16, 0, 0);
}

// [row][64-half] LDS tile, XOR-swizzled 16B granules within each 128B row
__device__ __forceinline__ int lds_off(int r, int g) {
    return (r << 6) + ((((g ^ r) & 7)) << 3);
}

// ---------------------------------------------------------------- pack (all)
// Layouts (columns of X buffers / rows of W packs use the SAME permutation):
//   X1 (KP1):  [w_prev 0..73 | inputs 73..76 | h1 76..476 | 0pad]
//   XA (KP1):  [h1n 0..400 | w_prev 400..473 | inputs 473..476 | 0pad]
//   X2 (KP23): [h1n 0..400 | inputs 400..403 | w 403..476 | h2 476..876 | 0pad]
//   X3 (KP23): [h2n 0..400 | inputs 400..403 | w 403..476 | h3 476..876 | 0pad]
// Gate interleave: dest row n = 4u+g  <-  src row g*400+u.
// Flat chunk decomposition, 8 cols per thread:
#define CW1   102400            // 1600 * 64
#define CW23  179200            // 1600 * 112
#define CWA   4096              // 64 * 64
#define CX1   262144            // 4096 * 64
#define CXA   57344             // 4096 * 14   (cols 400..512)
#define CX23  253952            // 4096 * 62   (cols 400..896, both X2 & X3)
#define O1    (CW1)
#define O2    (O1 + CW23)
#define O3    (O2 + CW23)
#define O4    (O3 + CWA)
#define O5    (O4 + CX1)
#define O6    (O5 + CXA)
#define O7    (O6 + CX23)       // 1038336 = 256 * 4056

__global__ __launch_bounds__(256) void pack_all(const float* __restrict__ Wih1,
                                                const float* __restrict__ Whh1,
                                                const float* __restrict__ Wih2,
                                                const float* __restrict__ Whh2,
                                                const float* __restrict__ Wih3,
                                                const float* __restrict__ Whh3,
                                                const float* __restrict__ W_attn,
                                                const float* __restrict__ w_prev,
                                                const float* __restrict__ inputs,
                                                const float* __restrict__ h1,
                                                const float* __restrict__ h2,
                                                const float* __restrict__ h3,
                                                _Float16* __restrict__ W1,
                                                _Float16* __restrict__ W2,
                                                _Float16* __restrict__ W3,
                                                _Float16* __restrict__ Wa,
                                                _Float16* __restrict__ X1,
                                                _Float16* __restrict__ XA,
                                                _Float16* __restrict__ X2,
                                                _Float16* __restrict__ X3)
{
    const int id = blockIdx.x * 256 + threadIdx.x;
    half8 hv;

    if (id < O1) {                       // ---- W1: 1600 x 512
        const int row = id >> 6;
        const int k0  = (id & 63) << 3;
        const int u = row >> 2, g = row & 3;
        const int src = g * 400 + u;
#pragma unroll
        for (int e = 0; e < 8; e++) {
            const int k = k0 + e;
            float x = 0.f;
            if (k < 76)           x = Wih1[(size_t)src * 76 + k];
            else if (k < 476)     x = Whh1[(size_t)src * 400 + (k - 76)];
            hv[e] = (_Float16)x;
        }
        *(half8*)(W1 + (size_t)row * KP1 + k0) = hv;
    } else if (id < O3) {                // ---- W2 / W3: 1600 x 896
        const int id2 = id - O1;
        const bool is3 = (id2 >= CW23);
        const int id3 = is3 ? id2 - CW23 : id2;
        const int row = id3 / 112;
        const int k0  = (id3 - row * 112) << 3;
        const int u = row >> 2, g = row & 3;
        const int src = g * 400 + u;
        const float* Wih = is3 ? Wih3 : Wih2;
        const float* Whh = is3 ? Whh3 : Whh2;
#pragma unroll
        for (int e = 0; e < 8; e++) {
            const int k = k0 + e;
            float x = 0.f;
            if (k < 400)          x = Wih[(size_t)src * 476 + 3 + k];
            else if (k < 403)     x = Wih[(size_t)src * 476 + (k - 400)];
            else if (k < 476)     x = Wih[(size_t)src * 476 + k];
            else if (k < 876)     x = Whh[(size_t)src * 400 + (k - 476)];
            hv[e] = (_Float16)x;
        }
        *(half8*)((is3 ? W3 : W2) + (size_t)row * KP23 + k0) = hv;
    } else if (id < O4) {                // ---- Wa: 64 x 512 (rows >=30 zero)
        const int id4 = id - O3;
        const int row = id4 >> 6;
        const int k0  = (id4 & 63) << 3;
#pragma unroll
        for (int e = 0; e < 8; e++) {
            const int k = k0 + e;
            float x = 0.f;
            if (row < 30) {
                if (k < 400)      x = W_attn[(size_t)row * 476 + 76 + k];
                else if (k < 473) x = W_attn[(size_t)row * 476 + (k - 400)];
                else if (k < 476) x = W_attn[(size_t)row * 476 + 73 + (k - 473)];
            }
            hv[e] = (_Float16)x;
        }
        *(half8*)(Wa + (size_t)row * KP1 + k0) = hv;
    } else if (id < O5) {                // ---- X1: 4096 x 512
        const int id5 = id - O4;
        const int b  = id5 >> 6;
        const int k0 = (id5 & 63) << 3;
#pragma unroll
        for (int e = 0; e < 8; e++) {
            const int k = k0 + e;
            float x = 0.f;
            if (k < 73)           x = w_prev[(size_t)b * 73 + k];
            else if (k < 76)      x = inputs[(size_t)b * 3 + (k - 73)];
            else if (k < 476)     x = h1[(size_t)b * 400 + (k - 76)];
            hv[e] = (_Float16)x;
        }
        *(half8*)(X1 + (size_t)b * KP1 + k0) = hv;
    } else if (id < O6) {                // ---- XA cols 400..512
        const int id6 = id - O5;
        const int b  = id6 / 14;
        const int k0 = 400 + ((id6 - b * 14) << 3);
#pragma unroll
        for (int e = 0; e < 8; e++) {
            const int k = k0 + e;
            float x = 0.f;
            if (k < 473)          x = w_prev[(size_t)b * 73 + (k - 400)];
            else if (k < 476)     x = inputs[(size_t)b * 3 + (k - 473)];
            hv[e] = (_Float16)x;
        }
        *(half8*)(XA + (size_t)b * KP1 + k0) = hv;
    } else if (id < O7) {                // ---- X2+X3 cols 400..896
        const int id7 = id - O6;
        const int b  = id7 / 62;
        const int k0 = 400 + ((id7 - b * 62) << 3);
        half8 h2v, h3v;
#pragma unroll
        for (int e = 0; e < 8; e++) {
            const int k = k0 + e;
            float x2 = 0.f, x3 = 0.f;
            if (k < 403)                    { x2 = inputs[(size_t)b * 3 + (k - 400)]; x3 = x2; }
            else if (k >= 476 && k < 876)   { x2 = h2[(size_t)b * 400 + (k - 476)];
                                              x3 = h3[(size_t)b * 400 + (k - 476)]; }
            h2v[e] = (_Float16)x2;
            h3v[e] = (_Float16)x3;
        }
        *(half8*)(X2 + (size_t)b * KP23 + k0) = h2v;
        *(half8*)(X3 + (size_t)b * KP23 + k0) = h3v;
    }
}

// ---------------------------------------------------------------- fused GEMM
// 64x128 tile: m = gate rows (4u+g interleaved), n = batch. BK=64, dbuf.
// Waves 2x2: each wave 32 rows x 64 batch = 2x4 frags.
template<int KP>
__global__ __launch_bounds__(256) void gemm_fused_t(const _Float16* __restrict__ Wm,
                                                    const _Float16* __restrict__ X,
                                                    const float* __restrict__ bias,
                                                    const float* __restrict__ c_in,
                                                    _Float16* __restrict__ d1, int ld1,
                                                    _Float16* __restrict__ d2, int ld2,
                                                    float* __restrict__ fout)
{
    __shared__ _Float16 As[2][64 * 64];    // W tile, 8 KB x2   (epilogue: Hs)
    __shared__ _Float16 Bs[2][128 * 64];   // X tile, 16 KB x2  (epilogue: Cs)

    const int t    = threadIdx.x;
    const int w    = t >> 6;
    const int lane = t & 63;
    const int quad = lane >> 4;
    const int l16  = lane & 15;
    const int m0   = blockIdx.y * 64;   // gate-row tile
    const int n0   = blockIdx.x * 128;  // batch tile
    const int wm   = (w >> 1) * 32;
    const int wn   = (w & 1) * 64;
    const int lr   = lane >> 3;             // 0..7 row-in-8
    const int gq   = (lane & 7) ^ lr;       // logical granule this lane fetches

    floatx4 acc[2][4] = {};

    auto stage = [&](int sb, int k0) {
        const int cr = w * 16;
#pragma unroll
        for (int s = 0; s < 2; s++)
            gload_lds16(Wm + (size_t)(m0 + cr + s * 8 + lr) * KP + k0 + gq * 8,
                        &As[sb][(cr + s * 8) * 64]);
#pragma unroll
        for (int j = 0; j < 2; j++) {
            const int cr2 = (j * 4 + w) * 16;
#pragma unroll
            for (int s = 0; s < 2; s++)
                gload_lds16(X + (size_t)(n0 + cr2 + s * 8 + lr) * KP + k0 + gq * 8,
                            &Bs[sb][(cr2 + s * 8) * 64]);
        }
    };

    stage(0, 0);
    constexpr int NT = KP / 64;
#pragma unroll
    for (int kt = 0; kt < NT; kt++) {
        const int sb = kt & 1;
        if (kt + 1 < NT) {
            stage(sb ^ 1, (kt + 1) * 64);   // 6 more in flight
            asm volatile("s_waitcnt vmcnt(6)" ::: "memory");
        } else {
            asm volatile("s_waitcnt vmcnt(0)" ::: "memory");
        }
        __builtin_amdgcn_s_barrier();
        __builtin_amdgcn_sched_barrier(0);

#pragma unroll
        for (int h = 0; h < 2; h++) {
            half8 af[2], bf[4];
#pragma unroll
            for (int i = 0; i < 2; i++)
                af[i] = *(const half8*)(&As[sb][lds_off(wm + i * 16 + l16, h * 4 + quad)]);
#pragma unroll
            for (int i = 0; i < 4; i++)
                bf[i] = *(const half8*)(&Bs[sb][lds_off(wn + i * 16 + l16, h * 4 + quad)]);
            __builtin_amdgcn_s_setprio(1);
#pragma unroll
            for (int mt = 0; mt < 2; mt++)
#pragma unroll
                for (int nt = 0; nt < 4; nt++)
                    acc[mt][nt] = __builtin_amdgcn_mfma_f32_16x16x32_f16(
                        af[mt], bf[nt], acc[mt][nt], 0, 0, 0);
            __builtin_amdgcn_s_setprio(0);
        }
        __builtin_amdgcn_s_barrier();
    }
    __builtin_amdgcn_sched_barrier(0);

    // ---------------- epilogue: descattered I/O via LDS transpose ----------
    const int u0 = m0 >> 2;                   // first unit of this block
    float*    Cs   = (float*)(&Bs[0][0]);     // [128][20] f32
    _Float16* Hs16 = (_Float16*)(&As[0][0]);  // [128][24] f16
    float*    Hs32 = (float*)(&As[0][0]);     // [128][20] f32
    {   // stage c tile, 2 x float4 per thread, 32B runs per batch row
        const int bl = t >> 1;
        const int j0 = (t & 1) * 2;
#pragma unroll
        for (int j = 0; j < 2; j++) {
            floatx4 cv = *(const floatx4*)(c_in + (size_t)(n0 + bl) * LSTM_N
                                           + u0 + (j0 + j) * 4);
            *(floatx4*)(Cs + bl * 20 + (j0 + j) * 4) = cv;
        }
    }
    __syncthreads();

#pragma unroll
    for (int mt = 0; mt < 2; mt++) {
        const int ul = (wm >> 2) + mt * 4 + quad;   // 0..15 local unit
        const int u  = u0 + ul;
        const float bi  = bias[u];
        const float bff = bias[400 + u];
        const float bg  = bias[800 + u];
        const float bo  = bias[1200 + u];
#pragma unroll
        for (int nt = 0; nt < 4; nt++) {
            const int bl = wn + nt * 16 + l16;      // local batch index
            float gi = acc[mt][nt][0] + bi;
            float gf = acc[mt][nt][1] + bff;
            float gg = acc[mt][nt][2] + bg;
            float go = acc[mt][nt][3] + bo;
            float si = 1.f / (1.f + expf(-gi));
            float sf = 1.f / (1.f + expf(-gf));
            float so = 1.f / (1.f + expf(-go));
            float cn = sf * Cs[bl * 20 + ul] + si * tanhf(gg);
            float h  = so * tanhf(cn);
            if (fout) Hs32[bl * 20 + ul] = h;
            else      Hs16[bl * 24 + ul] = (_Float16)h;
        }
    }
    __syncthreads();

    if (fout) {   // fp32 out: 64B per batch row, 2 x float4 per thread
        const int bl = t >> 1;
        const int p0 = (t & 1) * 2;
#pragma unroll
        for (int j = 0; j < 2; j++) {
            floatx4 hvv = *(const floatx4*)(Hs32 + bl * 20 + (p0 + j) * 4);
            *(floatx4*)(fout + (size_t)(n0 + bl) * LSTM_N + u0 + (p0 + j) * 4) = hvv;
        }
    } else {      // fp16: 32B per batch row, 1 x half8 per thread per dest
        const int bl = t >> 1;
        const int p  = t & 1;
        half8 hvv = *(const half8*)(Hs16 + bl * 24 + p * 8);
        *(half8*)(d1 + (size_t)(n0 + bl) * ld1 + u0 + p * 8) = hvv;
        if (d2) *(half8*)(d2 + (size_t)(n0 + bl) * ld2 + u0 + p * 8) = hvv;
    }
}

// ---------------------------------------------------------------- attn (fused)
// wave = one batch row; 4 waves/block; grid B/4.
// Phase 0 (NEW): attention-param GEMM as wave dot-products:
//   AP[b,m] = sum_k Wa[m,k] * XA[b,k] + b_attn[m],  m<30, K=512.
//   Wa rows 0..29 staged in LDS once per block; each lane holds an 8-col
//   slice of XA[b]; 30 dots -> butterfly reduce -> lane m keeps sum m.
__global__ __launch_bounds__(256) void attn_fused(const _Float16* __restrict__ Wa,
                                                  const _Float16* __restrict__ XA,
                                                  const float* __restrict__ b_attn,
                                                  const float* __restrict__ kappa,
                                                  const float* __restrict__ AV,
                                                  const int* __restrict__ alen,
                                                  _Float16* __restrict__ X2,
                                                  _Float16* __restrict__ X3)
{
    __shared__ _Float16 Wa_s[30 * KP1];     // 30 KB
    __shared__ float prm[4][32];
    __shared__ float phi_s[4][CHARLEN];

    const int t = threadIdx.x;
    // stage Wa rows 0..29 (1920 half8-chunks)
#pragma unroll
    for (int i = 0; i < 8; i++) {
        const int idx = t + i * 256;
        if (idx < 1920) {
            const int row = idx >> 6;
            const int c8  = (idx & 63) << 3;
            *(half8*)(&Wa_s[row * KP1 + c8]) = *(const half8*)(Wa + (size_t)row * KP1 + c8);
        }
    }
    __syncthreads();

    const int wave = t >> 6;
    const int lane = t & 63;
    const int b = blockIdx.x * 4 + wave;

    // this lane's 8-col slice of XA[b]
    half8 xa = *(const half8*)(XA + (size_t)b * KP1 + lane * 8);
    float xf[8];
#pragma unroll
    for (int e = 0; e < 8; e++) xf[e] = (float)xa[e];

    float myp = 0.f;
#pragma unroll
    for (int m = 0; m < 30; m++) {
        half8 wv = *(const half8*)(&Wa_s[m * KP1 + lane * 8]);
        float s = 0.f;
#pragma unroll
        for (int e = 0; e < 8; e++) s += (float)wv[e] * xf[e];
#pragma unroll
        for (int sh = 32; sh >= 1; sh >>= 1) s += __shfl_xor(s, sh, 64);
        if (lane == m) myp = s;          // predicated keep, no indexed array
    }

    if (lane < 30) {
        float p  = myp + b_attn[lane];
        float sp = (p > 20.f) ? p : log1pf(expf(p));
        float v;
        if (lane < 10)      v = sp;                          // alpha
        else if (lane < 20) v = fmaxf(sp, 0.01f);            // beta
        else                v = kappa[(size_t)b * NATTN + (lane - 20)] + sp * (1.f / 25.f);
        prm[wave][lane] = v;
    }
    __syncthreads();

    const int len = alen[b];
    {
        int c = lane;
        float phi = 0.f;
#pragma unroll
        for (int j = 0; j < NATTN; j++) {
            float d = prm[wave][20 + j] - (float)c;
            phi += prm[wave][j] * expf(-d * d / prm[wave][10 + j]);
        }
        phi_s[wave][c] = (c < len) ? phi : 0.f;
    }
    __syncthreads();

    for (int v0 = 0; v0 < VOCAB; v0 += 64) {   // VOCAB=73 > 64 lanes
        const int v = v0 + lane;
        if (v < VOCAB) {
            const float* avb = AV + (size_t)b * CHARLEN * VOCAB + v;
            float s = 0.f;
            for (int c = 0; c < len; c++)      // len is wave-uniform
                s += phi_s[wave][c] * avb[(size_t)c * VOCAB];
            _Float16 wv = (_Float16)s;
            X2[(size_t)b * KP23 + 403 + v] = wv;
            X3[(size_t)b * KP23 + 403 + v] = wv;
        }
    }
}

// ---------------------------------------------------------------- launch
extern "C" void kernel_launch(void* const* d_in, const int* in_sizes, int n_in,
                              void* d_out, int out_size, void* d_ws, size_t ws_size,
                              hipStream_t stream)
{
    const float* inputs = (const float*)d_in[0];
    const float* h1     = (const float*)d_in[1];
    const float* c1     = (const float*)d_in[2];
    const float* h2     = (const float*)d_in[3];
    const float* c2     = (const float*)d_in[4];
    const float* h3     = (const float*)d_in[5];
    const float* c3     = (const float*)d_in[6];
    const float* kappa  = (const float*)d_in[7];
    const float* w_prev = (const float*)d_in[8];
    const float* AV     = (const float*)d_in[9];
    const int*   alen   = (const int*)d_in[10];
    const float* W_ih1  = (const float*)d_in[11];
    const float* W_hh1  = (const float*)d_in[12];
    const float* b1     = (const float*)d_in[13];
    const float* W_attn = (const float*)d_in[14];
    const float* b_attn = (const float*)d_in[15];
    const float* W_ih2  = (const float*)d_in[16];
    const float* W_hh2  = (const float*)d_in[17];
    const float* b2     = (const float*)d_in[18];
    const float* W_ih3  = (const float*)d_in[19];
    const float* W_hh3  = (const float*)d_in[20];
    const float* b3     = (const float*)d_in[21];
    float* out = (float*)d_out;

    char* p = (char*)d_ws;
    _Float16* X1 = (_Float16*)p; p += (size_t)B_SZ * KP1 * 2;
    _Float16* XA = (_Float16*)p; p += (size_t)B_SZ * KP1 * 2;   // attn input
    _Float16* X2 = (_Float16*)p; p += (size_t)B_SZ * KP23 * 2;
    _Float16* X3 = (_Float16*)p; p += (size_t)B_SZ * KP23 * 2;
    _Float16* W1 = (_Float16*)p; p += (size_t)NG * KP1 * 2;
    _Float16* W2 = (_Float16*)p; p += (size_t)NG * KP23 * 2;
    _Float16* W3 = (_Float16*)p; p += (size_t)NG * KP23 * 2;
    _Float16* Wa = (_Float16*)p; p += (size_t)64 * KP1 * 2;

    pack_all<<<O7 / 256, 256, 0, stream>>>(W_ih1, W_hh1, W_ih2, W_hh2,
                                           W_ih3, W_hh3, W_attn,
                                           w_prev, inputs, h1, h2, h3,
                                           W1, W2, W3, Wa, X1, XA, X2, X3);

    const dim3 fgrid(B_SZ / 128, NG / 64);   // 32 batch-tiles x 25 row-tiles

    // LSTM1: h1n -> XA col 0 (attn input) + X2 col 0
    gemm_fused_t<KP1><<<fgrid, 256, 0, stream>>>(W1, X1, b1, c1,
                                                 XA, KP1, X2, KP23, nullptr);
    // attention: params (wave-dot GEMM) + phi + einsum -> w into X2, X3
    attn_fused<<<B_SZ / 4, 256, 0, stream>>>(Wa, XA, b_attn, kappa, AV, alen, X2, X3);
    // LSTM2: h2n -> X3 col 0
    gemm_fused_t<KP23><<<fgrid, 256, 0, stream>>>(W2, X2, b2, c2,
                                                  X3, KP23, nullptr, 0, nullptr);
    // LSTM3: h3n -> out (fp32)
    gemm_fused_t<KP23><<<fgrid, 256, 0, stream>>>(W3, X3, b3, c3,
                                                  nullptr, 0, nullptr, 0, out);
}

// Round 4
// 295.563 us; speedup vs baseline: 1.0481x; 1.0112x over previous
//
#include <hip/hip_runtime.h>
#include <hip/hip_bf16.h>

// Round 12: staging-BW attack (counters: MfmaUtil 7%, 269 MB staged @4.6TB/s):
//   - GEMM tiles 64x128 -> 128x256 (intensity 43 -> 85 FLOP/B), 512 thr,
//     8 waves x (64x64 = 4x4 frags); staging bytes halved
//   - XCD-aware block remap (batch-tile-major chunks): per-XCD working set
//     = 2 batch-tiles of X (0.9MB) + all W (2.9MB) < 4MB L2 -> L2-resident
//   - M padded to 1664 rows (13 tiles); guards at u>=400
//   - keeps dbuf + counted vmcnt(6) + setprio + descattered epilogue

#define B_SZ     4096
#define LSTM_N   400
#define MPAD     1664   // 13 * 128
#define MT       13     // row tiles
#define VOCAB    73
#define NATTN    10
#define CHARLEN  64
#define KP1      512
#define KP23     896

typedef _Float16 half8 __attribute__((ext_vector_type(8)));
typedef __attribute__((ext_vector_type(4))) float floatx4;

__device__ __forceinline__ void gload_lds16(const void* g, void* l) {
    __builtin_amdgcn_global_load_lds(
        (const __attribute__((address_space(1))) void*)g,
        (__attribute__((address_space(3))) void*)l, 16, 0, 0);
}

// [row][64-half] LDS tile, XOR-swizzled 16B granules within each 128B row
__device__ __forceinline__ int lds_off(int r, int g) {
    return (r << 6) + ((((g ^ r) & 7)) << 3);
}

// ---------------------------------------------------------------- pack (all)
// Layouts:
//   X1 (KP1):  [w_prev 0..73 | inputs 73..76 | h1 76..476 | 0pad]
//   XA (KP1):  [h1n 0..400 | w_prev 400..473 | inputs 473..476 | 0pad]
//   X2 (KP23): [h1n 0..400 | inputs 400..403 | w 403..476 | h2 476..876 | 0pad]
//   X3 (KP23): [h2n 0..400 | inputs 400..403 | w 403..476 | h3 476..876 | 0pad]
// W rows: n = 4u+g <- src row g*400+u; rows with u>=400 zero (M padding).
#define CW1   106496            // 1664 * 64
#define CW23  186368            // 1664 * 112
#define CWA   4096              // 64 * 64
#define CX1   262144            // 4096 * 64
#define CXA   57344             // 4096 * 14   (cols 400..512)
#define CX23  253952            // 4096 * 62   (cols 400..896, both X2 & X3)
#define O1    (CW1)
#define O2    (O1 + CW23)
#define O3    (O2 + CW23)
#define O4    (O3 + CWA)
#define O5    (O4 + CX1)
#define O6    (O5 + CXA)
#define O7    (O6 + CX23)       // 1056768 = 256 * 4128

__global__ __launch_bounds__(256) void pack_all(const float* __restrict__ Wih1,
                                                const float* __restrict__ Whh1,
                                                const float* __restrict__ Wih2,
                                                const float* __restrict__ Whh2,
                                                const float* __restrict__ Wih3,
                                                const float* __restrict__ Whh3,
                                                const float* __restrict__ W_attn,
                                                const float* __restrict__ w_prev,
                                                const float* __restrict__ inputs,
                                                const float* __restrict__ h1,
                                                const float* __restrict__ h2,
                                                const float* __restrict__ h3,
                                                _Float16* __restrict__ W1,
                                                _Float16* __restrict__ W2,
                                                _Float16* __restrict__ W3,
                                                _Float16* __restrict__ Wa,
                                                _Float16* __restrict__ X1,
                                                _Float16* __restrict__ XA,
                                                _Float16* __restrict__ X2,
                                                _Float16* __restrict__ X3)
{
    const int id = blockIdx.x * 256 + threadIdx.x;
    half8 hv;

    if (id < O1) {                       // ---- W1: 1664 x 512
        const int row = id >> 6;
        const int k0  = (id & 63) << 3;
        const int u = row >> 2, g = row & 3;
        const int src = g * 400 + u;
#pragma unroll
        for (int e = 0; e < 8; e++) {
            const int k = k0 + e;
            float x = 0.f;
            if (u < 400) {
                if (k < 76)           x = Wih1[(size_t)src * 76 + k];
                else if (k < 476)     x = Whh1[(size_t)src * 400 + (k - 76)];
            }
            hv[e] = (_Float16)x;
        }
        *(half8*)(W1 + (size_t)row * KP1 + k0) = hv;
    } else if (id < O3) {                // ---- W2 / W3: 1664 x 896
        const int id2 = id - O1;
        const bool is3 = (id2 >= CW23);
        const int id3 = is3 ? id2 - CW23 : id2;
        const int row = id3 / 112;
        const int k0  = (id3 - row * 112) << 3;
        const int u = row >> 2, g = row & 3;
        const int src = g * 400 + u;
        const float* Wih = is3 ? Wih3 : Wih2;
        const float* Whh = is3 ? Whh3 : Whh2;
#pragma unroll
        for (int e = 0; e < 8; e++) {
            const int k = k0 + e;
            float x = 0.f;
            if (u < 400) {
                if (k < 400)          x = Wih[(size_t)src * 476 + 3 + k];
                else if (k < 403)     x = Wih[(size_t)src * 476 + (k - 400)];
                else if (k < 476)     x = Wih[(size_t)src * 476 + k];
                else if (k < 876)     x = Whh[(size_t)src * 400 + (k - 476)];
            }
            hv[e] = (_Float16)x;
        }
        *(half8*)((is3 ? W3 : W2) + (size_t)row * KP23 + k0) = hv;
    } else if (id < O4) {                // ---- Wa: 64 x 512 (rows >=30 zero)
        const int id4 = id - O3;
        const int row = id4 >> 6;
        const int k0  = (id4 & 63) << 3;
#pragma unroll
        for (int e = 0; e < 8; e++) {
            const int k = k0 + e;
            float x = 0.f;
            if (row < 30) {
                if (k < 400)      x = W_attn[(size_t)row * 476 + 76 + k];
                else if (k < 473) x = W_attn[(size_t)row * 476 + (k - 400)];
                else if (k < 476) x = W_attn[(size_t)row * 476 + 73 + (k - 473)];
            }
            hv[e] = (_Float16)x;
        }
        *(half8*)(Wa + (size_t)row * KP1 + k0) = hv;
    } else if (id < O5) {                // ---- X1: 4096 x 512
        const int id5 = id - O4;
        const int b  = id5 >> 6;
        const int k0 = (id5 & 63) << 3;
#pragma unroll
        for (int e = 0; e < 8; e++) {
            const int k = k0 + e;
            float x = 0.f;
            if (k < 73)           x = w_prev[(size_t)b * 73 + k];
            else if (k < 76)      x = inputs[(size_t)b * 3 + (k - 73)];
            else if (k < 476)     x = h1[(size_t)b * 400 + (k - 76)];
            hv[e] = (_Float16)x;
        }
        *(half8*)(X1 + (size_t)b * KP1 + k0) = hv;
    } else if (id < O6) {                // ---- XA cols 400..512
        const int id6 = id - O5;
        const int b  = id6 / 14;
        const int k0 = 400 + ((id6 - b * 14) << 3);
#pragma unroll
        for (int e = 0; e < 8; e++) {
            const int k = k0 + e;
            float x = 0.f;
            if (k < 473)          x = w_prev[(size_t)b * 73 + (k - 400)];
            else if (k < 476)     x = inputs[(size_t)b * 3 + (k - 473)];
            hv[e] = (_Float16)x;
        }
        *(half8*)(XA + (size_t)b * KP1 + k0) = hv;
    } else if (id < O7) {                // ---- X2+X3 cols 400..896
        const int id7 = id - O6;
        const int b  = id7 / 62;
        const int k0 = 400 + ((id7 - b * 62) << 3);
        half8 h2v, h3v;
#pragma unroll
        for (int e = 0; e < 8; e++) {
            const int k = k0 + e;
            float x2 = 0.f, x3 = 0.f;
            if (k < 403)                    { x2 = inputs[(size_t)b * 3 + (k - 400)]; x3 = x2; }
            else if (k >= 476 && k < 876)   { x2 = h2[(size_t)b * 400 + (k - 476)];
                                              x3 = h3[(size_t)b * 400 + (k - 476)]; }
            h2v[e] = (_Float16)x2;
            h3v[e] = (_Float16)x3;
        }
        *(half8*)(X2 + (size_t)b * KP23 + k0) = h2v;
        *(half8*)(X3 + (size_t)b * KP23 + k0) = h3v;
    }
}

// ---------------------------------------------------------------- fused GEMM
// 128(rows) x 256(batch) tile, BK=64, dbuf, 512 threads = 8 waves (2m x 4n),
// each wave 64x64 = 4x4 frags. XCD remap: each XCD works 2 batch-tiles x all
// row-tiles -> W(2.9MB)+X-slice(0.9MB) fit 4MB per-XCD L2.
template<int KP>
__global__ __launch_bounds__(512) void gemm_fused_t(const _Float16* __restrict__ Wm,
                                                    const _Float16* __restrict__ X,
                                                    const float* __restrict__ bias,
                                                    const float* __restrict__ c_in,
                                                    _Float16* __restrict__ d1, int ld1,
                                                    _Float16* __restrict__ d2, int ld2,
                                                    float* __restrict__ fout)
{
    __shared__ _Float16 lds[2][(128 + 256) * 64];   // 96 KB: [A 16KB | B 32KB] x2

    const int t    = threadIdx.x;
    const int w    = t >> 6;
    const int lane = t & 63;
    const int quad = lane >> 4;
    const int l16  = lane & 15;
    // XCD-aware remap: xcd = hw_flat % 8 gets contiguous batch-tile-major chunk
    const int fid  = blockIdx.y * 16 + blockIdx.x;       // hw dispatch order
    const int work = (fid & 7) * 26 + (fid >> 3);        // 208 = 8 * 26
    const int bx   = work / MT;                          // batch tile 0..15
    const int by   = work - bx * MT;                     // row tile 0..12
    const int m0   = by * 128;
    const int n0   = bx * 256;
    const int wm   = (w >> 2) * 64;
    const int wn   = (w & 3) * 64;
    const int lr   = lane >> 3;             // 0..7 row-in-8
    const int gq   = (lane & 7) ^ lr;       // granule this lane fetches

    floatx4 acc[4][4] = {};

    // 6 global_load_lds per thread per K-step (2 A + 4 B)
    auto stage = [&](int sb, int k0) {
#pragma unroll
        for (int s = 0; s < 2; s++)
            gload_lds16(Wm + (size_t)(m0 + w * 16 + s * 8 + lr) * KP + k0 + gq * 8,
                        &lds[sb][(w * 16 + s * 8) * 64]);
#pragma unroll
        for (int s = 0; s < 4; s++)
            gload_lds16(X + (size_t)(n0 + w * 32 + s * 8 + lr) * KP + k0 + gq * 8,
                        &lds[sb][(128 + w * 32 + s * 8) * 64]);
    };

    stage(0, 0);
    constexpr int NT = KP / 64;
#pragma unroll
    for (int kt = 0; kt < NT; kt++) {
        const int sb = kt & 1;
        if (kt + 1 < NT) {
            stage(sb ^ 1, (kt + 1) * 64);
            asm volatile("s_waitcnt vmcnt(6)" ::: "memory");
        } else {
            asm volatile("s_waitcnt vmcnt(0)" ::: "memory");
        }
        __builtin_amdgcn_s_barrier();
        __builtin_amdgcn_sched_barrier(0);

#pragma unroll
        for (int h = 0; h < 2; h++) {
            half8 af[4], bf[4];
#pragma unroll
            for (int i = 0; i < 4; i++)
                af[i] = *(const half8*)(&lds[sb][lds_off(wm + i * 16 + l16, h * 4 + quad)]);
#pragma unroll
            for (int i = 0; i < 4; i++)
                bf[i] = *(const half8*)(&lds[sb][lds_off(128 + wn + i * 16 + l16, h * 4 + quad)]);
            __builtin_amdgcn_s_setprio(1);
#pragma unroll
            for (int mt = 0; mt < 4; mt++)
#pragma unroll
                for (int nt = 0; nt < 4; nt++)
                    acc[mt][nt] = __builtin_amdgcn_mfma_f32_16x16x32_f16(
                        af[mt], bf[nt], acc[mt][nt], 0, 0, 0);
            __builtin_amdgcn_s_setprio(0);
        }
        __builtin_amdgcn_s_barrier();
    }
    __builtin_amdgcn_sched_barrier(0);

    // ---------------- epilogue: descattered I/O via LDS transpose ----------
    const int u0     = by * 32;                       // first unit, 0..384
    const int nvalid = (u0 + 32 <= LSTM_N) ? 32 : (LSTM_N - u0);   // 32 or 16
    float*    Cs   = (float*)&lds[0][0];              // [256][36] f32, 36 KB
    _Float16* Hs16 = (_Float16*)&lds[1][0];           // [256][40] f16, 20 KB
    float*    Hs32 = (float*)&lds[1][0];              // [256][36] f32, 36 KB
    {   // stage c tile: 2 thr/row, 4 float4 each, guarded at u>=400
        const int bl = t >> 1;
        const int j0 = (t & 1) * 16;
#pragma unroll
        for (int j = 0; j < 4; j++) {
            const int ulc = j0 + j * 4;
            if (ulc < nvalid) {
                floatx4 cv = *(const floatx4*)(c_in + (size_t)(n0 + bl) * LSTM_N + u0 + ulc);
                *(floatx4*)(Cs + bl * 36 + ulc) = cv;
            }
        }
    }
    __syncthreads();

#pragma unroll
    for (int mt = 0; mt < 4; mt++) {
        const int ul = (wm >> 2) + mt * 4 + quad;     // 0..31 local unit
        const int u  = u0 + ul;
        const bool uv = ul < nvalid;
        const float bi  = uv ? bias[u] : 0.f;
        const float bff = uv ? bias[400 + u] : 0.f;
        const float bg  = uv ? bias[800 + u] : 0.f;
        const float bo  = uv ? bias[1200 + u] : 0.f;
#pragma unroll
        for (int nt = 0; nt < 4; nt++) {
            const int bl = wn + nt * 16 + l16;        // local batch index
            float gi = acc[mt][nt][0] + bi;
            float gf = acc[mt][nt][1] + bff;
            float gg = acc[mt][nt][2] + bg;
            float go = acc[mt][nt][3] + bo;
            float si = 1.f / (1.f + expf(-gi));
            float sf = 1.f / (1.f + expf(-gf));
            float so = 1.f / (1.f + expf(-go));
            float cn = sf * Cs[bl * 36 + ul] + si * tanhf(gg);
            float h  = so * tanhf(cn);
            if (uv) {
                if (fout) Hs32[bl * 36 + ul] = h;
                else      Hs16[bl * 40 + ul] = (_Float16)h;
            }
        }
    }
    __syncthreads();

    if (fout) {   // fp32: 2 thr/row, 4 float4 each
        const int bl = t >> 1;
        const int j0 = (t & 1) * 16;
#pragma unroll
        for (int j = 0; j < 4; j++) {
            const int ulc = j0 + j * 4;
            if (ulc < nvalid)
                *(floatx4*)(fout + (size_t)(n0 + bl) * LSTM_N + u0 + ulc) =
                    *(const floatx4*)(Hs32 + bl * 36 + ulc);
        }
    } else {      // fp16: 2 thr/row, 2 half8 each
        const int bl = t >> 1;
        const int j0 = (t & 1) * 16;
#pragma unroll
        for (int j = 0; j < 2; j++) {
            const int ulc = j0 + j * 8;
            if (ulc < nvalid) {
                half8 hvv = *(const half8*)(Hs16 + bl * 40 + ulc);
                *(half8*)(d1 + (size_t)(n0 + bl) * ld1 + u0 + ulc) = hvv;
                if (d2) *(half8*)(d2 + (size_t)(n0 + bl) * ld2 + u0 + ulc) = hvv;
            }
        }
    }
}

// ---------------------------------------------------------------- attn (fused)
// wave = one batch row; 4 waves/block; grid B/4.
// Phase 0: attention-param GEMM as wave dot-products (Wa rows in LDS).
__global__ __launch_bounds__(256) void attn_fused(const _Float16* __restrict__ Wa,
                                                  const _Float16* __restrict__ XA,
                                                  const float* __restrict__ b_attn,
                                                  const float* __restrict__ kappa,
                                                  const float* __restrict__ AV,
                                                  const int* __restrict__ alen,
                                                  _Float16* __restrict__ X2,
                                                  _Float16* __restrict__ X3)
{
    __shared__ _Float16 Wa_s[30 * KP1];     // 30 KB
    __shared__ float prm[4][32];
    __shared__ float phi_s[4][CHARLEN];

    const int t = threadIdx.x;
#pragma unroll
    for (int i = 0; i < 8; i++) {
        const int idx = t + i * 256;
        if (idx < 1920) {
            const int row = idx >> 6;
            const int c8  = (idx & 63) << 3;
            *(half8*)(&Wa_s[row * KP1 + c8]) = *(const half8*)(Wa + (size_t)row * KP1 + c8);
        }
    }
    __syncthreads();

    const int wave = t >> 6;
    const int lane = t & 63;
    const int b = blockIdx.x * 4 + wave;

    half8 xa = *(const half8*)(XA + (size_t)b * KP1 + lane * 8);
    float xf[8];
#pragma unroll
    for (int e = 0; e < 8; e++) xf[e] = (float)xa[e];

    float myp = 0.f;
#pragma unroll
    for (int m = 0; m < 30; m++) {
        half8 wv = *(const half8*)(&Wa_s[m * KP1 + lane * 8]);
        float s = 0.f;
#pragma unroll
        for (int e = 0; e < 8; e++) s += (float)wv[e] * xf[e];
#pragma unroll
        for (int sh = 32; sh >= 1; sh >>= 1) s += __shfl_xor(s, sh, 64);
        if (lane == m) myp = s;
    }

    if (lane < 30) {
        float p  = myp + b_attn[lane];
        float sp = (p > 20.f) ? p : log1pf(expf(p));
        float v;
        if (lane < 10)      v = sp;                          // alpha
        else if (lane < 20) v = fmaxf(sp, 0.01f);            // beta
        else                v = kappa[(size_t)b * NATTN + (lane - 20)] + sp * (1.f / 25.f);
        prm[wave][lane] = v;
    }
    __syncthreads();

    const int len = alen[b];
    {
        int c = lane;
        float phi = 0.f;
#pragma unroll
        for (int j = 0; j < NATTN; j++) {
            float d = prm[wave][20 + j] - (float)c;
            phi += prm[wave][j] * expf(-d * d / prm[wave][10 + j]);
        }
        phi_s[wave][c] = (c < len) ? phi : 0.f;
    }
    __syncthreads();

    for (int v0 = 0; v0 < VOCAB; v0 += 64) {
        const int v = v0 + lane;
        if (v < VOCAB) {
            const float* avb = AV + (size_t)b * CHARLEN * VOCAB + v;
            float s = 0.f;
            for (int c = 0; c < len; c++)
                s += phi_s[wave][c] * avb[(size_t)c * VOCAB];
            _Float16 wv = (_Float16)s;
            X2[(size_t)b * KP23 + 403 + v] = wv;
            X3[(size_t)b * KP23 + 403 + v] = wv;
        }
    }
}

// ---------------------------------------------------------------- launch
extern "C" void kernel_launch(void* const* d_in, const int* in_sizes, int n_in,
                              void* d_out, int out_size, void* d_ws, size_t ws_size,
                              hipStream_t stream)
{
    const float* inputs = (const float*)d_in[0];
    const float* h1     = (const float*)d_in[1];
    const float* c1     = (const float*)d_in[2];
    const float* h2     = (const float*)d_in[3];
    const float* c2     = (const float*)d_in[4];
    const float* h3     = (const float*)d_in[5];
    const float* c3     = (const float*)d_in[6];
    const float* kappa  = (const float*)d_in[7];
    const float* w_prev = (const float*)d_in[8];
    const float* AV     = (const float*)d_in[9];
    const int*   alen   = (const int*)d_in[10];
    const float* W_ih1  = (const float*)d_in[11];
    const float* W_hh1  = (const float*)d_in[12];
    const float* b1     = (const float*)d_in[13];
    const float* W_attn = (const float*)d_in[14];
    const float* b_attn = (const float*)d_in[15];
    const float* W_ih2  = (const float*)d_in[16];
    const float* W_hh2  = (const float*)d_in[17];
    const float* b2     = (const float*)d_in[18];
    const float* W_ih3  = (const float*)d_in[19];
    const float* W_hh3  = (const float*)d_in[20];
    const float* b3     = (const float*)d_in[21];
    float* out = (float*)d_out;

    char* p = (char*)d_ws;
    _Float16* X1 = (_Float16*)p; p += (size_t)B_SZ * KP1 * 2;
    _Float16* XA = (_Float16*)p; p += (size_t)B_SZ * KP1 * 2;
    _Float16* X2 = (_Float16*)p; p += (size_t)B_SZ * KP23 * 2;
    _Float16* X3 = (_Float16*)p; p += (size_t)B_SZ * KP23 * 2;
    _Float16* W1 = (_Float16*)p; p += (size_t)MPAD * KP1 * 2;
    _Float16* W2 = (_Float16*)p; p += (size_t)MPAD * KP23 * 2;
    _Float16* W3 = (_Float16*)p; p += (size_t)MPAD * KP23 * 2;
    _Float16* Wa = (_Float16*)p; p += (size_t)64 * KP1 * 2;

    pack_all<<<O7 / 256, 256, 0, stream>>>(W_ih1, W_hh1, W_ih2, W_hh2,
                                           W_ih3, W_hh3, W_attn,
                                           w_prev, inputs, h1, h2, h3,
                                           W1, W2, W3, Wa, X1, XA, X2, X3);

    const dim3 fgrid(B_SZ / 256, MT);   // 16 batch-tiles x 13 row-tiles = 208

    // LSTM1: h1n -> XA col 0 (attn input) + X2 col 0
    gemm_fused_t<KP1><<<fgrid, 512, 0, stream>>>(W1, X1, b1, c1,
                                                 XA, KP1, X2, KP23, nullptr);
    // attention: params (wave-dot GEMM) + phi + einsum -> w into X2, X3
    attn_fused<<<B_SZ / 4, 256, 0, stream>>>(Wa, XA, b_attn, kappa, AV, alen, X2, X3);
    // LSTM2: h2n -> X3 col 0
    gemm_fused_t<KP23><<<fgrid, 512, 0, stream>>>(W2, X2, b2, c2,
                                                  X3, KP23, nullptr, 0, nullptr);
    // LSTM3: h3n -> out (fp32)
    gemm_fused_t<KP23><<<fgrid, 512, 0, stream>>>(W3, X3, b3, c3,
                                                  nullptr, 0, nullptr, 0, out);
}

// Round 5
// 289.651 us; speedup vs baseline: 1.0695x; 1.0204x over previous
//
#include <hip/hip_runtime.h>
#include <hip/hip_bf16.h>

// Round 13: latency attack on the K-loop (R3 counters: ~1070cy/K-step vs
// ~300cy compute => ~800cy exposed load latency, depth-1 prefetch):
//   - back to 64x128 tile / 4 waves / 24KB per buffer (2 blocks/CU TLP)
//   - THREE LDS buffers, depth-2 prefetch: tile kt staged 2 iterations
//     ahead; steady-state s_waitcnt vmcnt(12) (18 loads in flight)
//   - bijective XCD remap (800 = 8x100): each XCD = 4 batch-tiles x 25
//     row-tiles -> W(2.9MB)+X-slice(0.9MB) < 4MB per-XCD L2
//   - keeps setprio, descattered epilogue, single pack, fused attn

#define B_SZ     4096
#define LSTM_N   400
#define NG       1600   // 4*LSTM
#define VOCAB    73
#define NATTN    10
#define CHARLEN  64
#define KP1      512
#define KP23     896

typedef _Float16 half8 __attribute__((ext_vector_type(8)));
typedef __attribute__((ext_vector_type(4))) float floatx4;

__device__ __forceinline__ void gload_lds16(const void* g, void* l) {
    __builtin_amdgcn_global_load_lds(
        (const __attribute__((address_space(1))) void*)g,
        (__attribute__((address_space(3))) void*)l, 16, 0, 0);
}

// [row][64-half] LDS tile, XOR-swizzled 16B granules within each 128B row
__device__ __forceinline__ int lds_off(int r, int g) {
    return (r << 6) + ((((g ^ r) & 7)) << 3);
}

// ---------------------------------------------------------------- pack (all)
// Layouts:
//   X1 (KP1):  [w_prev 0..73 | inputs 73..76 | h1 76..476 | 0pad]
//   XA (KP1):  [h1n 0..400 | w_prev 400..473 | inputs 473..476 | 0pad]
//   X2 (KP23): [h1n 0..400 | inputs 400..403 | w 403..476 | h2 476..876 | 0pad]
//   X3 (KP23): [h2n 0..400 | inputs 400..403 | w 403..476 | h3 476..876 | 0pad]
// W rows: n = 4u+g <- src row g*400+u.
#define CW1   102400            // 1600 * 64
#define CW23  179200            // 1600 * 112
#define CWA   4096              // 64 * 64
#define CX1   262144            // 4096 * 64
#define CXA   57344             // 4096 * 14   (cols 400..512)
#define CX23  253952            // 4096 * 62   (cols 400..896, both X2 & X3)
#define O1    (CW1)
#define O2    (O1 + CW23)
#define O3    (O2 + CW23)
#define O4    (O3 + CWA)
#define O5    (O4 + CX1)
#define O6    (O5 + CXA)
#define O7    (O6 + CX23)       // 1038336 = 256 * 4056

__global__ __launch_bounds__(256) void pack_all(const float* __restrict__ Wih1,
                                                const float* __restrict__ Whh1,
                                                const float* __restrict__ Wih2,
                                                const float* __restrict__ Whh2,
                                                const float* __restrict__ Wih3,
                                                const float* __restrict__ Whh3,
                                                const float* __restrict__ W_attn,
                                                const float* __restrict__ w_prev,
                                                const float* __restrict__ inputs,
                                                const float* __restrict__ h1,
                                                const float* __restrict__ h2,
                                                const float* __restrict__ h3,
                                                _Float16* __restrict__ W1,
                                                _Float16* __restrict__ W2,
                                                _Float16* __restrict__ W3,
                                                _Float16* __restrict__ Wa,
                                                _Float16* __restrict__ X1,
                                                _Float16* __restrict__ XA,
                                                _Float16* __restrict__ X2,
                                                _Float16* __restrict__ X3)
{
    const int id = blockIdx.x * 256 + threadIdx.x;
    half8 hv;

    if (id < O1) {                       // ---- W1: 1600 x 512
        const int row = id >> 6;
        const int k0  = (id & 63) << 3;
        const int u = row >> 2, g = row & 3;
        const int src = g * 400 + u;
#pragma unroll
        for (int e = 0; e < 8; e++) {
            const int k = k0 + e;
            float x = 0.f;
            if (k < 76)           x = Wih1[(size_t)src * 76 + k];
            else if (k < 476)     x = Whh1[(size_t)src * 400 + (k - 76)];
            hv[e] = (_Float16)x;
        }
        *(half8*)(W1 + (size_t)row * KP1 + k0) = hv;
    } else if (id < O3) {                // ---- W2 / W3: 1600 x 896
        const int id2 = id - O1;
        const bool is3 = (id2 >= CW23);
        const int id3 = is3 ? id2 - CW23 : id2;
        const int row = id3 / 112;
        const int k0  = (id3 - row * 112) << 3;
        const int u = row >> 2, g = row & 3;
        const int src = g * 400 + u;
        const float* Wih = is3 ? Wih3 : Wih2;
        const float* Whh = is3 ? Whh3 : Whh2;
#pragma unroll
        for (int e = 0; e < 8; e++) {
            const int k = k0 + e;
            float x = 0.f;
            if (k < 400)          x = Wih[(size_t)src * 476 + 3 + k];
            else if (k < 403)     x = Wih[(size_t)src * 476 + (k - 400)];
            else if (k < 476)     x = Wih[(size_t)src * 476 + k];
            else if (k < 876)     x = Whh[(size_t)src * 400 + (k - 476)];
            hv[e] = (_Float16)x;
        }
        *(half8*)((is3 ? W3 : W2) + (size_t)row * KP23 + k0) = hv;
    } else if (id < O4) {                // ---- Wa: 64 x 512 (rows >=30 zero)
        const int id4 = id - O3;
        const int row = id4 >> 6;
        const int k0  = (id4 & 63) << 3;
#pragma unroll
        for (int e = 0; e < 8; e++) {
            const int k = k0 + e;
            float x = 0.f;
            if (row < 30) {
                if (k < 400)      x = W_attn[(size_t)row * 476 + 76 + k];
                else if (k < 473) x = W_attn[(size_t)row * 476 + (k - 400)];
                else if (k < 476) x = W_attn[(size_t)row * 476 + 73 + (k - 473)];
            }
            hv[e] = (_Float16)x;
        }
        *(half8*)(Wa + (size_t)row * KP1 + k0) = hv;
    } else if (id < O5) {                // ---- X1: 4096 x 512
        const int id5 = id - O4;
        const int b  = id5 >> 6;
        const int k0 = (id5 & 63) << 3;
#pragma unroll
        for (int e = 0; e < 8; e++) {
            const int k = k0 + e;
            float x = 0.f;
            if (k < 73)           x = w_prev[(size_t)b * 73 + k];
            else if (k < 76)      x = inputs[(size_t)b * 3 + (k - 73)];
            else if (k < 476)     x = h1[(size_t)b * 400 + (k - 76)];
            hv[e] = (_Float16)x;
        }
        *(half8*)(X1 + (size_t)b * KP1 + k0) = hv;
    } else if (id < O6) {                // ---- XA cols 400..512
        const int id6 = id - O5;
        const int b  = id6 / 14;
        const int k0 = 400 + ((id6 - b * 14) << 3);
#pragma unroll
        for (int e = 0; e < 8; e++) {
            const int k = k0 + e;
            float x = 0.f;
            if (k < 473)          x = w_prev[(size_t)b * 73 + (k - 400)];
            else if (k < 476)     x = inputs[(size_t)b * 3 + (k - 473)];
            hv[e] = (_Float16)x;
        }
        *(half8*)(XA + (size_t)b * KP1 + k0) = hv;
    } else if (id < O7) {                // ---- X2+X3 cols 400..896
        const int id7 = id - O6;
        const int b  = id7 / 62;
        const int k0 = 400 + ((id7 - b * 62) << 3);
        half8 h2v, h3v;
#pragma unroll
        for (int e = 0; e < 8; e++) {
            const int k = k0 + e;
            float x2 = 0.f, x3 = 0.f;
            if (k < 403)                    { x2 = inputs[(size_t)b * 3 + (k - 400)]; x3 = x2; }
            else if (k >= 476 && k < 876)   { x2 = h2[(size_t)b * 400 + (k - 476)];
                                              x3 = h3[(size_t)b * 400 + (k - 476)]; }
            h2v[e] = (_Float16)x2;
            h3v[e] = (_Float16)x3;
        }
        *(half8*)(X2 + (size_t)b * KP23 + k0) = h2v;
        *(half8*)(X3 + (size_t)b * KP23 + k0) = h3v;
    }
}

// ---------------------------------------------------------------- fused GEMM
// 64x128 tile, 4 waves (2x2), each wave 32x64 = 2x4 frags. BK=64.
// 3 LDS buffers, depth-2 prefetch, steady-state vmcnt(12).
// XCD remap: 800 = 8 XCD x (4 batch-tiles x 25 row-tiles).
template<int KP>
__global__ __launch_bounds__(256) void gemm_fused_t(const _Float16* __restrict__ Wm,
                                                    const _Float16* __restrict__ X,
                                                    const float* __restrict__ bias,
                                                    const float* __restrict__ c_in,
                                                    _Float16* __restrict__ d1, int ld1,
                                                    _Float16* __restrict__ d2, int ld2,
                                                    float* __restrict__ fout)
{
    __shared__ _Float16 lds[3][192 * 64];   // 3 x 24KB: [A 64 rows | B 128 rows]

    const int t    = threadIdx.x;
    const int w    = t >> 6;
    const int lane = t & 63;
    const int quad = lane >> 4;
    const int l16  = lane & 15;
    // bijective XCD remap: fid%8 = XCD, each XCD gets 4 batch-tiles x 25 rows
    const int fid  = blockIdx.y * 32 + blockIdx.x;
    const int xcd  = fid & 7;
    const int loc  = fid >> 3;              // 0..99
    const int bx   = xcd * 4 + loc / 25;    // batch tile 0..31
    const int by   = loc % 25;              // row tile 0..24
    const int m0   = by * 64;
    const int n0   = bx * 128;
    const int wm   = (w >> 1) * 32;
    const int wn   = (w & 1) * 64;
    const int lr   = lane >> 3;             // 0..7 row-in-8
    const int gq   = (lane & 7) ^ lr;       // granule this lane fetches

    floatx4 acc[2][4] = {};

    // 6 global_load_lds per thread per K-step (2 W + 4 X)
    auto stage = [&](int sb, int k0) {
#pragma unroll
        for (int s = 0; s < 2; s++)
            gload_lds16(Wm + (size_t)(m0 + w * 16 + s * 8 + lr) * KP + k0 + gq * 8,
                        &lds[sb][(w * 16 + s * 8) * 64]);
#pragma unroll
        for (int s = 0; s < 4; s++)
            gload_lds16(X + (size_t)(n0 + w * 32 + s * 8 + lr) * KP + k0 + gq * 8,
                        &lds[sb][(64 + w * 32 + s * 8) * 64]);
    };

    stage(0, 0);
    stage(1, 64);
    constexpr int NT = KP / 64;
#pragma unroll
    for (int kt = 0; kt < NT; kt++) {
        const int sb = kt % 3;
        if (kt + 2 < NT) {
            stage((kt + 2) % 3, (kt + 2) * 64);       // depth-2: 18 in flight
            asm volatile("s_waitcnt vmcnt(12)" ::: "memory");  // drain tile kt
        } else if (kt + 1 < NT) {
            asm volatile("s_waitcnt vmcnt(6)" ::: "memory");
        } else {
            asm volatile("s_waitcnt vmcnt(0)" ::: "memory");
        }
        __builtin_amdgcn_s_barrier();
        __builtin_amdgcn_sched_barrier(0);

#pragma unroll
        for (int h = 0; h < 2; h++) {
            half8 af[2], bf[4];
#pragma unroll
            for (int i = 0; i < 2; i++)
                af[i] = *(const half8*)(&lds[sb][lds_off(wm + i * 16 + l16, h * 4 + quad)]);
#pragma unroll
            for (int i = 0; i < 4; i++)
                bf[i] = *(const half8*)(&lds[sb][lds_off(64 + wn + i * 16 + l16, h * 4 + quad)]);
            __builtin_amdgcn_s_setprio(1);
#pragma unroll
            for (int mt = 0; mt < 2; mt++)
#pragma unroll
                for (int nt = 0; nt < 4; nt++)
                    acc[mt][nt] = __builtin_amdgcn_mfma_f32_16x16x32_f16(
                        af[mt], bf[nt], acc[mt][nt], 0, 0, 0);
            __builtin_amdgcn_s_setprio(0);
        }
        __builtin_amdgcn_s_barrier();
    }
    __builtin_amdgcn_sched_barrier(0);

    // ---------------- epilogue: descattered I/O via LDS transpose ----------
    const int u0 = m0 >> 2;                   // first unit of this block
    float*    Cs   = (float*)&lds[0][0];      // [128][20] f32
    _Float16* Hs16 = (_Float16*)&lds[1][0];   // [128][24] f16
    float*    Hs32 = (float*)&lds[1][0];      // [128][20] f32
    {   // stage c tile, 2 x float4 per thread, 32B runs per batch row
        const int bl = t >> 1;
        const int j0 = (t & 1) * 2;
#pragma unroll
        for (int j = 0; j < 2; j++) {
            floatx4 cv = *(const floatx4*)(c_in + (size_t)(n0 + bl) * LSTM_N
                                           + u0 + (j0 + j) * 4);
            *(floatx4*)(Cs + bl * 20 + (j0 + j) * 4) = cv;
        }
    }
    __syncthreads();

#pragma unroll
    for (int mt = 0; mt < 2; mt++) {
        const int ul = (wm >> 2) + mt * 4 + quad;   // 0..15 local unit
        const int u  = u0 + ul;
        const float bi  = bias[u];
        const float bff = bias[400 + u];
        const float bg  = bias[800 + u];
        const float bo  = bias[1200 + u];
#pragma unroll
        for (int nt = 0; nt < 4; nt++) {
            const int bl = wn + nt * 16 + l16;      // local batch index
            float gi = acc[mt][nt][0] + bi;
            float gf = acc[mt][nt][1] + bff;
            float gg = acc[mt][nt][2] + bg;
            float go = acc[mt][nt][3] + bo;
            float si = 1.f / (1.f + expf(-gi));
            float sf = 1.f / (1.f + expf(-gf));
            float so = 1.f / (1.f + expf(-go));
            float cn = sf * Cs[bl * 20 + ul] + si * tanhf(gg);
            float h  = so * tanhf(cn);
            if (fout) Hs32[bl * 20 + ul] = h;
            else      Hs16[bl * 24 + ul] = (_Float16)h;
        }
    }
    __syncthreads();

    if (fout) {   // fp32 out: 64B per batch row, 2 x float4 per thread
        const int bl = t >> 1;
        const int p0 = (t & 1) * 2;
#pragma unroll
        for (int j = 0; j < 2; j++) {
            floatx4 hvv = *(const floatx4*)(Hs32 + bl * 20 + (p0 + j) * 4);
            *(floatx4*)(fout + (size_t)(n0 + bl) * LSTM_N + u0 + (p0 + j) * 4) = hvv;
        }
    } else {      // fp16: 32B per batch row, 1 x half8 per thread per dest
        const int bl = t >> 1;
        const int p  = t & 1;
        half8 hvv = *(const half8*)(Hs16 + bl * 24 + p * 8);
        *(half8*)(d1 + (size_t)(n0 + bl) * ld1 + u0 + p * 8) = hvv;
        if (d2) *(half8*)(d2 + (size_t)(n0 + bl) * ld2 + u0 + p * 8) = hvv;
    }
}

// ---------------------------------------------------------------- attn (fused)
// wave = one batch row; 4 waves/block; grid B/4.
// Phase 0: attention-param GEMM as wave dot-products (Wa rows in LDS).
__global__ __launch_bounds__(256) void attn_fused(const _Float16* __restrict__ Wa,
                                                  const _Float16* __restrict__ XA,
                                                  const float* __restrict__ b_attn,
                                                  const float* __restrict__ kappa,
                                                  const float* __restrict__ AV,
                                                  const int* __restrict__ alen,
                                                  _Float16* __restrict__ X2,
                                                  _Float16* __restrict__ X3)
{
    __shared__ _Float16 Wa_s[30 * KP1];     // 30 KB
    __shared__ float prm[4][32];
    __shared__ float phi_s[4][CHARLEN];

    const int t = threadIdx.x;
#pragma unroll
    for (int i = 0; i < 8; i++) {
        const int idx = t + i * 256;
        if (idx < 1920) {
            const int row = idx >> 6;
            const int c8  = (idx & 63) << 3;
            *(half8*)(&Wa_s[row * KP1 + c8]) = *(const half8*)(Wa + (size_t)row * KP1 + c8);
        }
    }
    __syncthreads();

    const int wave = t >> 6;
    const int lane = t & 63;
    const int b = blockIdx.x * 4 + wave;

    half8 xa = *(const half8*)(XA + (size_t)b * KP1 + lane * 8);
    float xf[8];
#pragma unroll
    for (int e = 0; e < 8; e++) xf[e] = (float)xa[e];

    float myp = 0.f;
#pragma unroll
    for (int m = 0; m < 30; m++) {
        half8 wv = *(const half8*)(&Wa_s[m * KP1 + lane * 8]);
        float s = 0.f;
#pragma unroll
        for (int e = 0; e < 8; e++) s += (float)wv[e] * xf[e];
#pragma unroll
        for (int sh = 32; sh >= 1; sh >>= 1) s += __shfl_xor(s, sh, 64);
        if (lane == m) myp = s;
    }

    if (lane < 30) {
        float p  = myp + b_attn[lane];
        float sp = (p > 20.f) ? p : log1pf(expf(p));
        float v;
        if (lane < 10)      v = sp;                          // alpha
        else if (lane < 20) v = fmaxf(sp, 0.01f);            // beta
        else                v = kappa[(size_t)b * NATTN + (lane - 20)] + sp * (1.f / 25.f);
        prm[wave][lane] = v;
    }
    __syncthreads();

    const int len = alen[b];
    {
        int c = lane;
        float phi = 0.f;
#pragma unroll
        for (int j = 0; j < NATTN; j++) {
            float d = prm[wave][20 + j] - (float)c;
            phi += prm[wave][j] * expf(-d * d / prm[wave][10 + j]);
        }
        phi_s[wave][c] = (c < len) ? phi : 0.f;
    }
    __syncthreads();

    for (int v0 = 0; v0 < VOCAB; v0 += 64) {
        const int v = v0 + lane;
        if (v < VOCAB) {
            const float* avb = AV + (size_t)b * CHARLEN * VOCAB + v;
            float s = 0.f;
            for (int c = 0; c < len; c++)
                s += phi_s[wave][c] * avb[(size_t)c * VOCAB];
            _Float16 wv = (_Float16)s;
            X2[(size_t)b * KP23 + 403 + v] = wv;
            X3[(size_t)b * KP23 + 403 + v] = wv;
        }
    }
}

// ---------------------------------------------------------------- launch
extern "C" void kernel_launch(void* const* d_in, const int* in_sizes, int n_in,
                              void* d_out, int out_size, void* d_ws, size_t ws_size,
                              hipStream_t stream)
{
    const float* inputs = (const float*)d_in[0];
    const float* h1     = (const float*)d_in[1];
    const float* c1     = (const float*)d_in[2];
    const float* h2     = (const float*)d_in[3];
    const float* c2     = (const float*)d_in[4];
    const float* h3     = (const float*)d_in[5];
    const float* c3     = (const float*)d_in[6];
    const float* kappa  = (const float*)d_in[7];
    const float* w_prev = (const float*)d_in[8];
    const float* AV     = (const float*)d_in[9];
    const int*   alen   = (const int*)d_in[10];
    const float* W_ih1  = (const float*)d_in[11];
    const float* W_hh1  = (const float*)d_in[12];
    const float* b1     = (const float*)d_in[13];
    const float* W_attn = (const float*)d_in[14];
    const float* b_attn = (const float*)d_in[15];
    const float* W_ih2  = (const float*)d_in[16];
    const float* W_hh2  = (const float*)d_in[17];
    const float* b2     = (const float*)d_in[18];
    const float* W_ih3  = (const float*)d_in[19];
    const float* W_hh3  = (const float*)d_in[20];
    const float* b3     = (const float*)d_in[21];
    float* out = (float*)d_out;

    char* p = (char*)d_ws;
    _Float16* X1 = (_Float16*)p; p += (size_t)B_SZ * KP1 * 2;
    _Float16* XA = (_Float16*)p; p += (size_t)B_SZ * KP1 * 2;
    _Float16* X2 = (_Float16*)p; p += (size_t)B_SZ * KP23 * 2;
    _Float16* X3 = (_Float16*)p; p += (size_t)B_SZ * KP23 * 2;
    _Float16* W1 = (_Float16*)p; p += (size_t)NG * KP1 * 2;
    _Float16* W2 = (_Float16*)p; p += (size_t)NG * KP23 * 2;
    _Float16* W3 = (_Float16*)p; p += (size_t)NG * KP23 * 2;
    _Float16* Wa = (_Float16*)p; p += (size_t)64 * KP1 * 2;

    pack_all<<<O7 / 256, 256, 0, stream>>>(W_ih1, W_hh1, W_ih2, W_hh2,
                                           W_ih3, W_hh3, W_attn,
                                           w_prev, inputs, h1, h2, h3,
                                           W1, W2, W3, Wa, X1, XA, X2, X3);

    const dim3 fgrid(32, 25);   // 800 blocks = 8 XCD x 100

    // LSTM1: h1n -> XA col 0 (attn input) + X2 col 0
    gemm_fused_t<KP1><<<fgrid, 256, 0, stream>>>(W1, X1, b1, c1,
                                                 XA, KP1, X2, KP23, nullptr);
    // attention: params (wave-dot GEMM) + phi + einsum -> w into X2, X3
    attn_fused<<<B_SZ / 4, 256, 0, stream>>>(Wa, XA, b_attn, kappa, AV, alen, X2, X3);
    // LSTM2: h2n -> X3 col 0
    gemm_fused_t<KP23><<<fgrid, 256, 0, stream>>>(W2, X2, b2, c2,
                                                  X3, KP23, nullptr, 0, nullptr);
    // LSTM3: h3n -> out (fp32)
    gemm_fused_t<KP23><<<fgrid, 256, 0, stream>>>(W3, X3, b3, c3,
                                                  nullptr, 0, nullptr, 0, out);
}